// Round 10
// baseline (212.551 us; speedup 1.0000x reference)
//
#include <hip/hip_runtime.h>

#define DEVFN __device__ __forceinline__

DEVFN float sgnf(float x) { return (x > 0.f) ? 1.f : ((x < 0.f) ? -1.f : 0.f); }

// round-to-nearest-even fp32 -> bf16 bits
DEVFN unsigned short f2bf(float x) {
  unsigned int u = __float_as_uint(x);
  unsigned int r = (u + 0x7fffu + ((u >> 16) & 1u)) >> 16;
  return (unsigned short)r;
}

typedef __attribute__((ext_vector_type(8))) short short8;
typedef __attribute__((ext_vector_type(4))) float f32x4;
typedef __attribute__((ext_vector_type(2))) float f32x2;
typedef __attribute__((ext_vector_type(4))) unsigned int u32x4;

// ---- workspace layout ----
// double region (BN stat accumulators, 64 contention slots per channel)
#define SUM1 0        // 6*64 doubles
#define SQ1  384
#define SUM2 768      // 16*64
#define SQ2  1792
#define SUM3 2816     // 120*64
#define SQ3  10496
#define DBL_BYTES 145408  // 18176 doubles

// float region offsets (in floats, from fbase = ws + DBL_BYTES)
#define WFR_OFF  3584    // conv3 weights, bf16 frag image: 102400 ushort
#define WFR2_OFF 54784   // fc1 weights, bf16 frag image: 24576 ushort
#define H1_OFF   69632                  // 8192*1176 (pooled pre-BN layer1)
#define H2_OFF   (H1_OFF + 8192*1176)   // 8192*400  (pooled pre-BN layer2)
#define Y3_OFF   (H2_OFF + 8192*400)    // 8192*120  (pre-BN layer3)
// conv2 weight frag image (15 chunks x 64 lanes x 8 ushort = 7680) is
// ALIASED into the head of y3: written by prep, read by conv2_mfma,
// overwritten later by conv3_mfma. Stream-order safe, zero ws growth.

// conv2 staged-image geometry (u32 = hi|lo bf16 packed pixel).
// SINGLE copy, ODD row stride 17 (odd stride self-scrambles banks — the
// round-6 even-stride dual-copy variant hit 14.6M bank conflicts).
#define RS 17        // row stride: px(<=9) + kx(<=7) -> 17 cols; 14..16 zero
#define PLANE 238    // 14 * RS
#define IMGP 1428    // 6 * PLANE

// conv1 grid split: 1366 conv blocks (6 imgs each; last has 2) + 400 prep.
// R9 lesson: occupancy is GRID-limited, not LDS-limited — use more small
// blocks. 6 imgs -> LDS 27.1 KB -> 6 blocks/CU (24 waves static), grid
// 1366 = 5.3/CU, items 504/256 thr = 98% intra-block balance.
#define C1_NB 1366

// ---------------- layer 1 fused + weight-prep tail blocks ------------------
// blocks [0,1366): conv1 (conv + stats + pre-BN maxpool), image-PAIR packed
// via v_pk_fma_f32. blocks [1366,1766): binarize/frag-image prep.
// LAUNCH BOUNDS NOTE (round-8 regression): 2nd arg = MIN BLOCKS/CU on this
// toolchain. (256,4) -> VGPR cap 128; body uses ~64 (proven, no spill).
__global__ __launch_bounds__(256, 4) void conv1_prep(
    const float* __restrict__ x, const float* __restrict__ w1,
    const float* __restrict__ b1, float* __restrict__ m1,
    double* __restrict__ sums, const float* __restrict__ w2,
    const float* __restrict__ w3, const float* __restrict__ f1,
    unsigned short* __restrict__ wfr3, unsigned short* __restrict__ wfr,
    unsigned short* __restrict__ wfr2) {
  __shared__ f32x2 simg[3 * 1088];   // 3 img-pairs x 32 rows x 34 (pad)
  __shared__ float swtp[6 * 40];     // [ch][ky][8 pad] aligned weight rows
  __shared__ float red[6], redq[6];
  int tid = threadIdx.x;
  if (blockIdx.x >= C1_NB) {  // ---- prep path ----
    int i = (blockIdx.x - C1_NB) * 256 + tid;
    if (i < 7680) {  // conv2 frag image: kp = c*32 + 8g + j, k = kp>>1
      int j = i & 7;
      int t = i >> 3;
      int l = t & 63;
      int c = t >> 6;            // 0..14
      int ch = l & 15;
      int kp = c * 32 + ((l >> 4) << 3) + j;
      int k = kp >> 1;           // padded k, 0..239
      int b = k >> 3, kx = k & 7;
      int ci = b / 5, ky = b - 5 * ci;
      float v = (kx < 5) ? sgnf(w2[(ch * 6 + ci) * 25 + ky * 5 + kx]) : 0.f;
      wfr3[i] = f2bf(v);  // exact for -1/0/+1
    }
    if (i < 102400) {  // conv3 frag image: k' = c*32 + 8g + j, k = k'>>1
      int j = i & 7;
      int t = i >> 3;
      int l = t & 63;
      int cc = (t >> 6) % 25;
      int nt = (t >> 6) / 25;
      int ch = nt * 16 + (l & 15);
      int kp = cc * 32 + ((l >> 4) << 3) + j;
      float v = (ch < 120) ? sgnf(w3[ch * 400 + (kp >> 1)]) : 0.f;
      wfr[i] = f2bf(v);
    }
    if (i < 24576) {  // fc1 frag image: 6 nt x 8 c x 64 lane x 8
      int j = i & 7;
      int t = i >> 3;
      int l = t & 63;
      int cc = (t >> 6) & 7;
      int nt = t >> 9;
      int col = nt * 16 + (l & 15);
      int kp = cc * 32 + ((l >> 4) << 3) + j;
      int k = kp >> 1;
      float v = (col < 84 && k < 120) ? sgnf(f1[col * 120 + k]) : 0.f;
      wfr2[i] = f2bf(v);
    }
    return;
  }
  // ---- conv1 path ----
  int img0 = blockIdx.x * 6;
  int nimg = 8192 - img0;
  if (nimg > 6) nimg = 6;
  int npair = nimg >> 1;   // 3, or 1 in the tail block
  {
    const float2* xg = (const float2*)(x + (size_t)img0 * 1024);
    int lim = npair * 1024;  // nimg * 512 float2
    for (int i2 = tid; i2 < lim; i2 += 256) {
      int img = i2 >> 9;   // 0..5
      int j = i2 & 511;
      float2 v = xg[img * 512 + j];
      int p = img >> 1, q = img & 1;
      int row = j >> 4, col = (j & 15) * 2;
      float* d0 = (float*)&simg[p * 1088 + row * 34 + col];
      d0[q] = v.x;
      d0[2 + q] = v.y;
    }
  }
  for (int i = tid; i < 240; i += 256) {  // [ch][ky][8]: kx<5 valid
    int ch = i / 40, r = i - ch * 40;
    int ky = r >> 3, kx = r & 7;
    swtp[i] = (kx < 5) ? w1[ch * 25 + ky * 5 + kx] : 0.f;
  }
  if (tid < 6) { red[tid] = 0.f; redq[tid] = 0.f; }
  __syncthreads();

  // items = npair x 14 pool-rows x 2 col-halves x 6 ch (ch fastest ->
  // rb reads broadcast across the 6-ch lane groups). 504 = 256*1.97.
  int nitem = npair * 168;
  for (int idx = tid; idx < nitem; idx += 256) {
    int ch = idx % 6;
    int t = idx / 6;
    int h = t & 1;
    int t2 = t >> 1;
    int py = t2 % 14;
    int p = t2 / 14;
    float bb = b1[ch];
    f32x2 acc0[14], acc1[14];
#pragma unroll
    for (int o = 0; o < 14; ++o) {
      acc0[o] = (f32x2){bb, bb};
      acc1[o] = (f32x2){bb, bb};
    }
    const f32x2* ibase = &simg[p * 1088 + h * 14];
    const float* wch = &swtp[ch * 40];
#pragma unroll
    for (int d = 0; d < 6; ++d) {
      int row = 2 * py + d;
      f32x2 rb[18];
      const f32x4* rp = (const f32x4*)(ibase + row * 34);  // 16B aligned
#pragma unroll
      for (int tt = 0; tt < 9; ++tt) {
        f32x4 v = rp[tt];
        rb[2 * tt] = (f32x2){v.x, v.y};
        rb[2 * tt + 1] = (f32x2){v.z, v.w};
      }
      if (d < 5) {
        const float* wrow = wch + d * 8;
        f32x4 w4 = *(const f32x4*)wrow;   // 32B-aligned row
        float w5[5] = {w4.x, w4.y, w4.z, w4.w, wrow[4]};
#pragma unroll
        for (int kx = 0; kx < 5; ++kx) {
          f32x2 ws = {w5[kx], w5[kx]};
#pragma unroll
          for (int o = 0; o < 14; ++o)
            acc0[o] = __builtin_elementwise_fma(rb[o + kx], ws, acc0[o]);
        }
      }
      if (d >= 1) {
        const float* wrow = wch + (d - 1) * 8;
        f32x4 w4 = *(const f32x4*)wrow;
        float w5[5] = {w4.x, w4.y, w4.z, w4.w, wrow[4]};
#pragma unroll
        for (int kx = 0; kx < 5; ++kx) {
          f32x2 ws = {w5[kx], w5[kx]};
#pragma unroll
          for (int o = 0; o < 14; ++o)
            acc1[o] = __builtin_elementwise_fma(rb[o + kx], ws, acc1[o]);
        }
      }
    }
    // stats over this thread's 2 rows x 14 cols x 2 images
    f32x2 sv = {0.f, 0.f}, qv = {0.f, 0.f};
#pragma unroll
    for (int o = 0; o < 14; ++o) {
      f32x2 a0 = acc0[o], a1 = acc1[o];
      sv += a0; sv += a1;
      qv = __builtin_elementwise_fma(a0, a0, qv);
      qv = __builtin_elementwise_fma(a1, a1, qv);
    }
    atomicAdd(&red[ch], sv.x + sv.y);
    atomicAdd(&redq[ch], qv.x + qv.y);
    // pre-BN 2x2 maxpool, both images at once
    float* mpA = m1 + (size_t)(img0 + 2 * p) * 1176 + ch * 196 + py * 14 + h * 7;
    float* mpB = mpA + 1176;
#pragma unroll
    for (int j = 0; j < 7; ++j) {
      f32x2 m = __builtin_elementwise_max(
          __builtin_elementwise_max(acc0[2 * j], acc0[2 * j + 1]),
          __builtin_elementwise_max(acc1[2 * j], acc1[2 * j + 1]));
      mpA[j] = m.x;
      mpB[j] = m.y;
    }
  }
  __syncthreads();
  if (tid < 6) {
    int slot = blockIdx.x & 63;
    atomicAdd(&sums[SUM1 + tid * 64 + slot], (double)red[tid]);
    atomicAdd(&sums[SQ1 + tid * 64 + slot], (double)redq[tid]);
  }
}

// ---------------- layer 2 as implicit-GEMM MFMA (round-4 proven LDS
// geometry: single copy, odd stride 17, 4x b32 A-frag reads). BN1 scales
// computed IN-KERNEL (producer completed by stream order; every block does
// the identical deterministic slot reduction).
__global__ __launch_bounds__(256, 4) void conv2_mfma(
    const float* __restrict__ m1, const unsigned short* __restrict__ wfr3,
    const float* __restrict__ b2, double* __restrict__ sums,
    float* __restrict__ m2) {
  __shared__ unsigned int Aim[4 * IMGP];  // 22.8 KB
  __shared__ float sa1[6], sc1[6];
  __shared__ float red[16], redq[16];
  int tid = threadIdx.x;
  int img0 = blockIdx.x * 4;
  if (tid < 6) {  // in-kernel BN1 finalize (no gamma/beta, eps 1e-4)
    const double* ps = sums + SUM1 + tid * 64;
    const double* pq = sums + SQ1 + tid * 64;
    double s = 0.0, q = 0.0;
#pragma unroll 8
    for (int i = 0; i < 64; ++i) { s += ps[i]; q += pq[i]; }
    double mean = s * (1.0 / (8192.0 * 784.0));
    double var = q * (1.0 / (8192.0 * 784.0)) - mean * mean;
    float inv = (float)(1.0 / sqrt(var + 1e-4));
    sa1[tid] = inv;
    sc1[tid] = -(float)mean * inv;
  }
  if (tid < 16) { red[tid] = 0.f; redq[tid] = 0.f; }
  // zero pad cols 14..16 (read only under zero weights; must be finite)
  for (int i = tid; i < 1008; i += 256) {
    int c3 = i - (i / 3) * 3;
    int t = i / 3;
    int row = t % 14;
    int t2 = t / 14;
    int ci = t2 % 6, img = t2 / 6;
    Aim[img * IMGP + ci * PLANE + row * RS + 14 + c3] = 0u;
  }
  __syncthreads();  // scales + pads ready
  {
    const float2* mg = (const float2*)(m1 + (size_t)img0 * 1176);
    for (int i2 = tid; i2 < 2352; i2 += 256) {
      int img = i2 / 588;
      int e = (i2 - img * 588) * 2;  // even element in [0,1176)
      int pl = e / 196;
      int rr = e - pl * 196;
      int row = rr / 14, col = rr - row * 14;  // col even, col+1 <= 13
      float a = sa1[pl], c = sc1[pl];
      float2 v = mg[i2];
      float v0 = fmaxf(fmaf(a, v.x, c), 0.f);
      float v1 = fmaxf(fmaf(a, v.y, c), 0.f);
      unsigned int h0 = f2bf(v0);
      unsigned int l0 = f2bf(v0 - __uint_as_float(h0 << 16));
      unsigned int h1 = f2bf(v1);
      unsigned int l1 = f2bf(v1 - __uint_as_float(h1 << 16));
      unsigned int* dst = &Aim[img * IMGP + pl * PLANE + row * RS + col];
      dst[0] = h0 | (l0 << 16);
      dst[1] = h1 | (l1 << 16);
    }
  }
  __syncthreads();

  int lane = tid & 63;
  int wv = tid >> 6;
  const short8* bvec = (const short8*)wfr3;
  short8 bf[15];
#pragma unroll
  for (int c = 0; c < 15; ++c) bf[c] = bvec[c * 64 + lane];
  int ch = lane & 15;       // = A-row-in-tile AND output channel (C col)
  int ag = lane >> 4;       // k-group
  int agh = ag >> 1, agl = ag & 1;
  float bb = b2[ch];
  float s0 = 0.f, q0 = 0.f;

  for (int t = wv; t < 25; t += 4) {
    // A-read row: position p = t*16 + (lane&15), pool-block order
    int prd = t * 16 + ch;
    int imr = prd / 100;
    int pos = prd - imr * 100;
    int pb = pos >> 2, q = pos & 3;
    int pyr = pb / 5;
    int py = 2 * pyr + (q >> 1);
    int px = 2 * (pb - pyr * 5) + (q & 1);
    const unsigned int* base = &Aim[imr * IMGP + py * RS + px + agl * 4];
    const unsigned int* bR = base + agh * RS;    // block step within ci
    const unsigned int* bW = base + agh * 170;   // ky4 -> ky0, ci+1 wrap
    f32x4 acc = {0.f, 0.f, 0.f, 0.f};
#pragma unroll
    for (int c = 0; c < 15; ++c) {
      const int b0 = 2 * c;
      const int ci0 = b0 / 5, ky0 = b0 % 5;      // compile-time
      const unsigned int* pc =
          ((ky0 == 4) ? bW : bR) + (ci0 * PLANE + ky0 * RS);
      unsigned int a0 = pc[0], a1 = pc[1], a2 = pc[2], a3 = pc[3];
      union { u32x4 u; short8 s; } ua;
      ua.u = (u32x4){a0, a1, a2, a3};
      acc = __builtin_amdgcn_mfma_f32_16x16x32_bf16(ua.s, bf[c], acc, 0, 0, 0);
    }
    // lane's 4 C-rows = one 2x2 pool window (pool-block order)
    int po = t * 4 + ag;
    int imo = po / 25;
    int pbl = po - imo * 25;
    float v0 = acc[0] + bb, v1 = acc[1] + bb;
    float v2 = acc[2] + bb, v3 = acc[3] + bb;
    s0 += (v0 + v1) + (v2 + v3);
    q0 = fmaf(v0, v0, q0); q0 = fmaf(v1, v1, q0);
    q0 = fmaf(v2, v2, q0); q0 = fmaf(v3, v3, q0);
    float mx = fmaxf(fmaxf(v0, v1), fmaxf(v2, v3));
    m2[(size_t)(img0 + imo) * 400 + ch * 25 + pbl] = mx;
  }
  s0 += __shfl_xor(s0, 16, 64); q0 += __shfl_xor(q0, 16, 64);
  s0 += __shfl_xor(s0, 32, 64); q0 += __shfl_xor(q0, 32, 64);
  if (ag == 0) {
    atomicAdd(&red[ch], s0);
    atomicAdd(&redq[ch], q0);
  }
  __syncthreads();
  if (tid < 16) {
    int slot = blockIdx.x & 63;
    atomicAdd(&sums[SUM2 + tid * 64 + slot], (double)red[tid]);
    atomicAdd(&sums[SQ2 + tid * 64 + slot], (double)redq[tid]);
  }
}

// ---------------- layer 3: MFMA bf16-split GEMM — BN2 finalize in-kernel,
// whole A-tile staged once, barrier-free 25-chunk MFMA loop.
__global__ __launch_bounds__(256) void conv3_mfma(
    const float* __restrict__ m2, const unsigned short* __restrict__ wfr,
    const float* __restrict__ b3, const float* __restrict__ bn2_g,
    const float* __restrict__ bn2_b, double* __restrict__ sums,
    float* __restrict__ y3) {
  __shared__ unsigned int Alds[16 * 404];  // 25.9 KB
  __shared__ float sa2[16], sc2[16];
  __shared__ float red[128], redq[128];
  int tid = threadIdx.x;
  int img0 = blockIdx.x * 16;
  if (tid < 16) {  // in-kernel BN2 finalize (affine, eps 1e-4)
    const double* ps = sums + SUM2 + tid * 64;
    const double* pq = sums + SQ2 + tid * 64;
    double s = 0.0, q = 0.0;
#pragma unroll 8
    for (int i = 0; i < 64; ++i) { s += ps[i]; q += pq[i]; }
    double mean = s * (1.0 / (8192.0 * 100.0));
    double var = q * (1.0 / (8192.0 * 100.0)) - mean * mean;
    float inv = (float)(1.0 / sqrt(var + 1e-4));
    float g = fmaxf(bn2_g[tid], 0.01f);
    float av = g * inv;
    sa2[tid] = av;
    sc2[tid] = bn2_b[tid] - (float)mean * av;
  }
  if (tid < 128) { red[tid] = 0.f; redq[tid] = 0.f; }
  __syncthreads();
  // stage: 16 imgs x 400 k, BN2+relu, hi/lo pack -> u32
  for (int i4 = tid; i4 < 1600; i4 += 256) {
    int img = i4 / 100, k4 = i4 - img * 100;
    int k = 4 * k4;
    float4 v = *(const float4*)(m2 + (size_t)(img0 + img) * 400 + k);
    float vv[4] = {v.x, v.y, v.z, v.w};
    unsigned int pk[4];
#pragma unroll
    for (int e = 0; e < 4; ++e) {
      int ch = ((k + e) * 41) >> 10;  // /25
      float val = fmaxf(fmaf(sa2[ch], vv[e], sc2[ch]), 0.f);
      unsigned int hb = f2bf(val);
      float vh = __uint_as_float(hb << 16);
      unsigned int lb = f2bf(val - vh);
      pk[e] = hb | (lb << 16);
    }
    unsigned int* dst = &Alds[img * 404 + k];
    dst[0] = pk[0]; dst[1] = pk[1]; dst[2] = pk[2]; dst[3] = pk[3];
  }
  __syncthreads();

  int lane = tid & 63;
  int wv = tid >> 6;
  int nt0 = wv * 2, nt1 = wv * 2 + 1;
  const short8* bvec = (const short8*)wfr;
  int arow = lane & 15;
  int ag = lane >> 4;
  f32x4 acc0 = {0.f, 0.f, 0.f, 0.f}, acc1 = {0.f, 0.f, 0.f, 0.f};
  const unsigned short* abase =
      (const unsigned short*)&Alds[arow * 404 + ag * 4];
#pragma unroll 5
  for (int c = 0; c < 25; ++c) {
    short8 af = *(const short8*)(abase + c * 32);  // 16B aligned
    short8 b0 = bvec[(nt0 * 25 + c) * 64 + lane];
    short8 b1 = bvec[(nt1 * 25 + c) * 64 + lane];
    acc0 = __builtin_amdgcn_mfma_f32_16x16x32_bf16(af, b0, acc0, 0, 0, 0);
    acc1 = __builtin_amdgcn_mfma_f32_16x16x32_bf16(af, b1, acc1, 0, 0, 0);
  }
  int chA = nt0 * 16 + (lane & 15);
  int chB = nt1 * 16 + (lane & 15);
  int rbase = img0 + ((lane >> 4) << 2);
  {
    float bias = b3[chA];
    float s = 0.f, q = 0.f;
#pragma unroll
    for (int r = 0; r < 4; ++r) {
      float v = acc0[r] + bias;
      y3[(size_t)(rbase + r) * 120 + chA] = v;
      s += v; q = fmaf(v, v, q);
    }
    atomicAdd(&red[chA], s);
    atomicAdd(&redq[chA], q);
  }
  if (chB < 120) {
    float bias = b3[chB];
    float s = 0.f, q = 0.f;
#pragma unroll
    for (int r = 0; r < 4; ++r) {
      float v = acc1[r] + bias;
      y3[(size_t)(rbase + r) * 120 + chB] = v;
      s += v; q = fmaf(v, v, q);
    }
    atomicAdd(&red[chB], s);
    atomicAdd(&redq[chB], q);
  }
  __syncthreads();
  if (tid < 120) {
    int slot = blockIdx.x & 63;
    atomicAdd(&sums[SUM3 + tid * 64 + slot], (double)red[tid]);
    atomicAdd(&sums[SQ3 + tid * 64 + slot], (double)redq[tid]);
  }
}

// ---------------- fc: BN3 finalize in-kernel -> BN3+relu -> MFMA fc1 ->
// relu -> fc2. block 192 = 3 waves x 2 N-tiles. 16 imgs/block.
__global__ __launch_bounds__(192) void fc_mfma(
    const float* __restrict__ y3, const double* __restrict__ sums,
    const float* __restrict__ bn3_g, const float* __restrict__ bn3_b,
    const unsigned short* __restrict__ wfr2, const float* __restrict__ b1,
    const float* __restrict__ w2, const float* __restrict__ b2,
    float* __restrict__ out) {
  __shared__ unsigned int Alds[16 * 132];  // [img][k 0..127 pad] u32 hi|lo
  __shared__ float sh4[16 * 88];
  __shared__ float sw2[10 * 85];
  __shared__ float sa3[120], sc3[120];
  __shared__ float sb1[84], sb2[10];
  int tid = threadIdx.x;
  int img0 = blockIdx.x * 16;
  if (tid < 120) {  // in-kernel BN3 finalize (affine, eps 1e-5)
    const double* ps = sums + SUM3 + tid * 64;
    const double* pq = sums + SQ3 + tid * 64;
    double s = 0.0, q = 0.0;
#pragma unroll 8
    for (int i = 0; i < 64; ++i) { s += ps[i]; q += pq[i]; }
    double mean = s * (1.0 / 8192.0);
    double var = q * (1.0 / 8192.0) - mean * mean;
    float inv = (float)(1.0 / sqrt(var + 1e-5));
    float g = fmaxf(bn3_g[tid], 0.01f);
    float av = g * inv;
    sa3[tid] = av;
    sc3[tid] = bn3_b[tid] - (float)mean * av;
  }
  if (tid < 84) sb1[tid] = b1[tid];
  if (tid >= 84 && tid < 94) sb2[tid - 84] = b2[tid - 84];
  for (int i = tid; i < 850; i += 192) {
    int o = i / 85, k = i - o * 85;
    sw2[i] = (k < 84) ? w2[o * 84 + k] : 0.f;
  }
  __syncthreads();
  // stage: 16 imgs x 128 k (120 valid, pad zero), BN3+relu, hi/lo pack
  for (int i4 = tid; i4 < 512; i4 += 192) {
    int img = i4 >> 5, k4 = i4 & 31;
    int k = 4 * k4;
    unsigned int pk[4] = {0u, 0u, 0u, 0u};
    if (k4 < 30) {
      float4 v = *(const float4*)(y3 + (size_t)(img0 + img) * 120 + k);
      float vv[4] = {v.x, v.y, v.z, v.w};
#pragma unroll
      for (int e = 0; e < 4; ++e) {
        float val = fmaxf(fmaf(sa3[k + e], vv[e], sc3[k + e]), 0.f);
        unsigned int hb = f2bf(val);
        float vh = __uint_as_float(hb << 16);
        unsigned int lb = f2bf(val - vh);
        pk[e] = hb | (lb << 16);
      }
    }
    unsigned int* dst = &Alds[img * 132 + k];
    dst[0] = pk[0]; dst[1] = pk[1]; dst[2] = pk[2]; dst[3] = pk[3];
  }
  __syncthreads();

  int lane = tid & 63;
  int wv = tid >> 6;  // 0..2
  int nt0 = wv * 2, nt1 = wv * 2 + 1;
  const short8* bvec = (const short8*)wfr2;
  int arow = lane & 15;
  int ag = lane >> 4;
  f32x4 acc0 = {0.f, 0.f, 0.f, 0.f}, acc1 = {0.f, 0.f, 0.f, 0.f};
  const unsigned short* abase =
      (const unsigned short*)&Alds[arow * 132 + ag * 4];
#pragma unroll
  for (int c = 0; c < 8; ++c) {
    short8 af = *(const short8*)(abase + c * 32);
    short8 b0 = bvec[(nt0 * 8 + c) * 64 + lane];
    short8 b1 = bvec[(nt1 * 8 + c) * 64 + lane];
    acc0 = __builtin_amdgcn_mfma_f32_16x16x32_bf16(af, b0, acc0, 0, 0, 0);
    acc1 = __builtin_amdgcn_mfma_f32_16x16x32_bf16(af, b1, acc1, 0, 0, 0);
  }
  // h4 = relu(fc1 + b1) into LDS
  {
    int jA = nt0 * 16 + (lane & 15);  // <= 79, always valid
    int jB = nt1 * 16 + (lane & 15);  // may exceed 83
    int r0 = (lane >> 4) << 2;
#pragma unroll
    for (int r = 0; r < 4; ++r)
      sh4[(r0 + r) * 88 + jA] = fmaxf(acc0[r] + sb1[jA], 0.f);
    if (jB < 84) {
#pragma unroll
      for (int r = 0; r < 4; ++r)
        sh4[(r0 + r) * 88 + jB] = fmaxf(acc1[r] + sb1[jB], 0.f);
    }
  }
  __syncthreads();
  // fc2: 160 threads, one (img, out) each
  if (tid < 160) {
    int img = tid / 10, o = tid - (tid / 10) * 10;
    float acc = sb2[o];
    const float* hp = &sh4[img * 88];
    const float* wp = &sw2[o * 85];
#pragma unroll 4
    for (int k = 0; k < 84; ++k) acc = fmaf(hp[k], wp[k], acc);
    out[(size_t)(img0 + img) * 10 + o] = acc;
  }
}

extern "C" void kernel_launch(void* const* d_in, const int* in_sizes, int n_in,
                              void* d_out, int out_size, void* d_ws,
                              size_t ws_size, hipStream_t stream) {
  const float* x = (const float*)d_in[0];
  const float* conv1_w = (const float*)d_in[1];
  const float* conv1_b = (const float*)d_in[2];
  const float* conv2_w = (const float*)d_in[3];
  const float* conv2_b = (const float*)d_in[4];
  const float* bn2_g = (const float*)d_in[5];
  const float* bn2_b = (const float*)d_in[6];
  const float* conv3_w = (const float*)d_in[7];
  const float* conv3_b = (const float*)d_in[8];
  const float* bn3_g = (const float*)d_in[9];
  const float* bn3_b = (const float*)d_in[10];
  const float* fc1_w = (const float*)d_in[11];
  const float* fc1_b = (const float*)d_in[12];
  const float* fc2_w = (const float*)d_in[13];
  const float* fc2_b = (const float*)d_in[14];
  float* out = (float*)d_out;

  double* sums = (double*)d_ws;
  float* fbase = (float*)((char*)d_ws + DBL_BYTES);
  unsigned short* wfr = (unsigned short*)(fbase + WFR_OFF);
  unsigned short* wfr2 = (unsigned short*)(fbase + WFR2_OFF);
  float* m1 = fbase + H1_OFF;
  float* m2 = fbase + H2_OFF;
  float* y3 = fbase + Y3_OFF;
  unsigned short* wfr3 = (unsigned short*)y3;  // aliased; see layout note

  hipMemsetAsync(d_ws, 0, DBL_BYTES, stream);

  conv1_prep<<<1766, 256, 0, stream>>>(x, conv1_w, conv1_b, m1, sums, conv2_w,
                                       conv3_w, fc1_w, wfr3, wfr, wfr2);
  conv2_mfma<<<2048, 256, 0, stream>>>(m1, wfr3, conv2_b, sums, m2);
  conv3_mfma<<<512, 256, 0, stream>>>(m2, wfr, conv3_b, bn2_g, bn2_b, sums,
                                      y3);
  fc_mfma<<<512, 192, 0, stream>>>(y3, sums, bn3_g, bn3_b, wfr2, fc1_b, fc2_w,
                                   fc2_b, out);
}

// Round 11
// 199.632 us; speedup vs baseline: 1.0647x; 1.0647x over previous
//
#include <hip/hip_runtime.h>

#define DEVFN __device__ __forceinline__

DEVFN float sgnf(float x) { return (x > 0.f) ? 1.f : ((x < 0.f) ? -1.f : 0.f); }

// round-to-nearest-even fp32 -> bf16 bits
DEVFN unsigned short f2bf(float x) {
  unsigned int u = __float_as_uint(x);
  unsigned int r = (u + 0x7fffu + ((u >> 16) & 1u)) >> 16;
  return (unsigned short)r;
}

typedef __attribute__((ext_vector_type(8))) short short8;
typedef __attribute__((ext_vector_type(4))) float f32x4;
typedef __attribute__((ext_vector_type(2))) float f32x2;
typedef __attribute__((ext_vector_type(4))) unsigned int u32x4;

// ---- workspace layout ----
// double region (BN stat accumulators, 64 contention slots per channel)
#define SUM1 0        // 6*64 doubles
#define SQ1  384
#define SUM2 768      // 16*64
#define SQ2  1792
#define SUM3 2816     // 120*64
#define SQ3  10496
#define DBL_BYTES 145408  // 18176 doubles

// float region offsets (in floats, from fbase = ws + DBL_BYTES)
#define WFR_OFF  3584    // conv3 weights, bf16 frag image: 102400 ushort
#define WFR2_OFF 54784   // fc1 weights, bf16 frag image: 24576 ushort
#define H1_OFF   69632                  // 8192*1176 (pooled pre-BN layer1)
#define H2_OFF   (H1_OFF + 8192*1176)   // 8192*400  (pooled pre-BN layer2)
#define Y3_OFF   (H2_OFF + 8192*400)    // 8192*120  (pre-BN layer3)
// conv2 weight frag image (15 chunks x 64 lanes x 8 ushort = 7680) is
// ALIASED into the head of y3: written by prep, read by conv2_mfma,
// overwritten later by conv3_mfma. Stream-order safe, zero ws growth.

// conv2 staged-image geometry (u32 = hi|lo bf16 packed pixel).
// SINGLE copy, ODD row stride 17 (odd stride self-scrambles banks — the
// round-6 even-stride dual-copy variant hit 14.6M bank conflicts).
#define RS 17        // row stride: px(<=9) + kx(<=7) -> 17 cols; 14..16 zero
#define PLANE 238    // 14 * RS
#define IMGP 1428    // 6 * PLANE

// conv1 grid split: 1024 conv blocks (8 imgs, R7-proven geometry) + 400 prep
// R8/R9/R10 lesson: occupancy knobs don't move conv1 — it is latency-bound
// on the rb WAR hazard (single rb buffer serializes row loads behind FMAs;
// VGPR=64 proved the compiler allocated one buffer). This version breaks
// the hazard with an explicit rb double-buffer (prefetch row d+1 while
// computing row d).
#define C1_NB 1024

// ---------------- layer 1 fused + weight-prep tail blocks ------------------
// blocks [0,1024): conv1 (conv + stats + pre-BN maxpool), image-PAIR packed
// via v_pk_fma_f32, rb double-buffered. blocks [1024,1424): prep.
// LAUNCH BOUNDS NOTE: 2nd arg = MIN BLOCKS/CU on this toolchain (R8
// regression). (256,3) -> 12 waves/CU -> VGPR cap ~170; body needs ~150.
__global__ __launch_bounds__(256, 3) void conv1_prep(
    const float* __restrict__ x, const float* __restrict__ w1,
    const float* __restrict__ b1, float* __restrict__ m1,
    double* __restrict__ sums, const float* __restrict__ w2,
    const float* __restrict__ w3, const float* __restrict__ f1,
    unsigned short* __restrict__ wfr3, unsigned short* __restrict__ wfr,
    unsigned short* __restrict__ wfr2) {
  __shared__ f32x2 simg[4 * 1088];   // 4 img-pairs x 32 rows x 34 (pad)
  __shared__ float swtp[6 * 40];     // [ch][ky][8 pad] aligned weight rows
  __shared__ float red[6], redq[6];
  int tid = threadIdx.x;
  if (blockIdx.x >= C1_NB) {  // ---- prep path ----
    int i = (blockIdx.x - C1_NB) * 256 + tid;
    if (i < 7680) {  // conv2 frag image: kp = c*32 + 8g + j, k = kp>>1
      int j = i & 7;
      int t = i >> 3;
      int l = t & 63;
      int c = t >> 6;            // 0..14
      int ch = l & 15;
      int kp = c * 32 + ((l >> 4) << 3) + j;
      int k = kp >> 1;           // padded k, 0..239
      int b = k >> 3, kx = k & 7;
      int ci = b / 5, ky = b - 5 * ci;
      float v = (kx < 5) ? sgnf(w2[(ch * 6 + ci) * 25 + ky * 5 + kx]) : 0.f;
      wfr3[i] = f2bf(v);  // exact for -1/0/+1
    }
    if (i < 102400) {  // conv3 frag image: k' = c*32 + 8g + j, k = k'>>1
      int j = i & 7;
      int t = i >> 3;
      int l = t & 63;
      int cc = (t >> 6) % 25;
      int nt = (t >> 6) / 25;
      int ch = nt * 16 + (l & 15);
      int kp = cc * 32 + ((l >> 4) << 3) + j;
      float v = (ch < 120) ? sgnf(w3[ch * 400 + (kp >> 1)]) : 0.f;
      wfr[i] = f2bf(v);
    }
    if (i < 24576) {  // fc1 frag image: 6 nt x 8 c x 64 lane x 8
      int j = i & 7;
      int t = i >> 3;
      int l = t & 63;
      int cc = (t >> 6) & 7;
      int nt = t >> 9;
      int col = nt * 16 + (l & 15);
      int kp = cc * 32 + ((l >> 4) << 3) + j;
      int k = kp >> 1;
      float v = (col < 84 && k < 120) ? sgnf(f1[col * 120 + k]) : 0.f;
      wfr2[i] = f2bf(v);
    }
    return;
  }
  // ---- conv1 path ----
  int img0 = blockIdx.x * 8;
  {
    const float2* xg = (const float2*)(x + (size_t)img0 * 1024);
    for (int i2 = tid; i2 < 4096; i2 += 256) {
      int img = i2 >> 9;   // 0..7
      int j = i2 & 511;
      float2 v = xg[img * 512 + j];
      int p = img >> 1, q = img & 1;
      int row = j >> 4, col = (j & 15) * 2;
      float* d0 = (float*)&simg[p * 1088 + row * 34 + col];
      d0[q] = v.x;
      d0[2 + q] = v.y;
    }
  }
  for (int i = tid; i < 240; i += 256) {  // [ch][ky][8]: kx<5 valid
    int ch = i / 40, r = i - ch * 40;
    int ky = r >> 3, kx = r & 7;
    swtp[i] = (kx < 5) ? w1[ch * 25 + ky * 5 + kx] : 0.f;
  }
  if (tid < 6) { red[tid] = 0.f; redq[tid] = 0.f; }
  __syncthreads();

  // items = 4 pairs x 14 pool-rows x 2 col-halves x 6 ch (ch fastest ->
  // rb reads broadcast across the 6-ch lane groups)
  for (int idx = tid; idx < 672; idx += 256) {
    int ch = idx % 6;
    int t = idx / 6;
    int h = t & 1;
    int t2 = t >> 1;
    int py = t2 % 14;
    int p = t2 / 14;
    float bb = b1[ch];
    f32x2 acc0[14], acc1[14];
#pragma unroll
    for (int o = 0; o < 14; ++o) {
      acc0[o] = (f32x2){bb, bb};
      acc1[o] = (f32x2){bb, bb};
    }
    const f32x2* ibase = &simg[p * 1088 + h * 14];
    const float* wch = &swtp[ch * 40];
    // rb double-buffer: prefetch row d+1 while computing row d (breaks the
    // WAR hazard that serialized each row's LDS loads behind prior FMAs).
    f32x2 rb[2][18];
    {
      const f32x4* rp = (const f32x4*)(ibase + (2 * py) * 34);
#pragma unroll
      for (int tt = 0; tt < 9; ++tt) {
        f32x4 v = rp[tt];
        rb[0][2 * tt] = (f32x2){v.x, v.y};
        rb[0][2 * tt + 1] = (f32x2){v.z, v.w};
      }
    }
#pragma unroll
    for (int d = 0; d < 6; ++d) {
      if (d < 5) {  // prefetch next input row into the alternate buffer
        const f32x4* rp = (const f32x4*)(ibase + (2 * py + d + 1) * 34);
#pragma unroll
        for (int tt = 0; tt < 9; ++tt) {
          f32x4 v = rp[tt];
          rb[(d + 1) & 1][2 * tt] = (f32x2){v.x, v.y};
          rb[(d + 1) & 1][2 * tt + 1] = (f32x2){v.z, v.w};
        }
      }
      const f32x2* rc = rb[d & 1];
      if (d < 5) {
        const float* wrow = wch + d * 8;
        f32x4 w4 = *(const f32x4*)wrow;   // 32B-aligned row
        float w5[5] = {w4.x, w4.y, w4.z, w4.w, wrow[4]};
#pragma unroll
        for (int kx = 0; kx < 5; ++kx) {
          f32x2 ws = {w5[kx], w5[kx]};
#pragma unroll
          for (int o = 0; o < 14; ++o)
            acc0[o] = __builtin_elementwise_fma(rc[o + kx], ws, acc0[o]);
        }
      }
      if (d >= 1) {
        const float* wrow = wch + (d - 1) * 8;
        f32x4 w4 = *(const f32x4*)wrow;
        float w5[5] = {w4.x, w4.y, w4.z, w4.w, wrow[4]};
#pragma unroll
        for (int kx = 0; kx < 5; ++kx) {
          f32x2 ws = {w5[kx], w5[kx]};
#pragma unroll
          for (int o = 0; o < 14; ++o)
            acc1[o] = __builtin_elementwise_fma(rc[o + kx], ws, acc1[o]);
        }
      }
    }
    // stats over this thread's 2 rows x 14 cols x 2 images
    f32x2 sv = {0.f, 0.f}, qv = {0.f, 0.f};
#pragma unroll
    for (int o = 0; o < 14; ++o) {
      f32x2 a0 = acc0[o], a1 = acc1[o];
      sv += a0; sv += a1;
      qv = __builtin_elementwise_fma(a0, a0, qv);
      qv = __builtin_elementwise_fma(a1, a1, qv);
    }
    atomicAdd(&red[ch], sv.x + sv.y);
    atomicAdd(&redq[ch], qv.x + qv.y);
    // pre-BN 2x2 maxpool, both images at once
    float* mpA = m1 + (size_t)(img0 + 2 * p) * 1176 + ch * 196 + py * 14 + h * 7;
    float* mpB = mpA + 1176;
#pragma unroll
    for (int j = 0; j < 7; ++j) {
      f32x2 m = __builtin_elementwise_max(
          __builtin_elementwise_max(acc0[2 * j], acc0[2 * j + 1]),
          __builtin_elementwise_max(acc1[2 * j], acc1[2 * j + 1]));
      mpA[j] = m.x;
      mpB[j] = m.y;
    }
  }
  __syncthreads();
  if (tid < 6) {
    int slot = blockIdx.x & 63;
    atomicAdd(&sums[SUM1 + tid * 64 + slot], (double)red[tid]);
    atomicAdd(&sums[SQ1 + tid * 64 + slot], (double)redq[tid]);
  }
}

// ---------------- layer 2 as implicit-GEMM MFMA (round-4 proven LDS
// geometry: single copy, odd stride 17, 4x b32 A-frag reads). BN1 scales
// computed IN-KERNEL (producer completed by stream order; every block does
// the identical deterministic slot reduction).
__global__ __launch_bounds__(256, 4) void conv2_mfma(
    const float* __restrict__ m1, const unsigned short* __restrict__ wfr3,
    const float* __restrict__ b2, double* __restrict__ sums,
    float* __restrict__ m2) {
  __shared__ unsigned int Aim[4 * IMGP];  // 22.8 KB
  __shared__ float sa1[6], sc1[6];
  __shared__ float red[16], redq[16];
  int tid = threadIdx.x;
  int img0 = blockIdx.x * 4;
  if (tid < 6) {  // in-kernel BN1 finalize (no gamma/beta, eps 1e-4)
    const double* ps = sums + SUM1 + tid * 64;
    const double* pq = sums + SQ1 + tid * 64;
    double s = 0.0, q = 0.0;
#pragma unroll 8
    for (int i = 0; i < 64; ++i) { s += ps[i]; q += pq[i]; }
    double mean = s * (1.0 / (8192.0 * 784.0));
    double var = q * (1.0 / (8192.0 * 784.0)) - mean * mean;
    float inv = (float)(1.0 / sqrt(var + 1e-4));
    sa1[tid] = inv;
    sc1[tid] = -(float)mean * inv;
  }
  if (tid < 16) { red[tid] = 0.f; redq[tid] = 0.f; }
  // zero pad cols 14..16 (read only under zero weights; must be finite)
  for (int i = tid; i < 1008; i += 256) {
    int c3 = i - (i / 3) * 3;
    int t = i / 3;
    int row = t % 14;
    int t2 = t / 14;
    int ci = t2 % 6, img = t2 / 6;
    Aim[img * IMGP + ci * PLANE + row * RS + 14 + c3] = 0u;
  }
  __syncthreads();  // scales + pads ready
  {
    const float2* mg = (const float2*)(m1 + (size_t)img0 * 1176);
    for (int i2 = tid; i2 < 2352; i2 += 256) {
      int img = i2 / 588;
      int e = (i2 - img * 588) * 2;  // even element in [0,1176)
      int pl = e / 196;
      int rr = e - pl * 196;
      int row = rr / 14, col = rr - row * 14;  // col even, col+1 <= 13
      float a = sa1[pl], c = sc1[pl];
      float2 v = mg[i2];
      float v0 = fmaxf(fmaf(a, v.x, c), 0.f);
      float v1 = fmaxf(fmaf(a, v.y, c), 0.f);
      unsigned int h0 = f2bf(v0);
      unsigned int l0 = f2bf(v0 - __uint_as_float(h0 << 16));
      unsigned int h1 = f2bf(v1);
      unsigned int l1 = f2bf(v1 - __uint_as_float(h1 << 16));
      unsigned int* dst = &Aim[img * IMGP + pl * PLANE + row * RS + col];
      dst[0] = h0 | (l0 << 16);
      dst[1] = h1 | (l1 << 16);
    }
  }
  __syncthreads();

  int lane = tid & 63;
  int wv = tid >> 6;
  const short8* bvec = (const short8*)wfr3;
  short8 bf[15];
#pragma unroll
  for (int c = 0; c < 15; ++c) bf[c] = bvec[c * 64 + lane];
  int ch = lane & 15;       // = A-row-in-tile AND output channel (C col)
  int ag = lane >> 4;       // k-group
  int agh = ag >> 1, agl = ag & 1;
  float bb = b2[ch];
  float s0 = 0.f, q0 = 0.f;

  for (int t = wv; t < 25; t += 4) {
    // A-read row: position p = t*16 + (lane&15), pool-block order
    int prd = t * 16 + ch;
    int imr = prd / 100;
    int pos = prd - imr * 100;
    int pb = pos >> 2, q = pos & 3;
    int pyr = pb / 5;
    int py = 2 * pyr + (q >> 1);
    int px = 2 * (pb - pyr * 5) + (q & 1);
    const unsigned int* base = &Aim[imr * IMGP + py * RS + px + agl * 4];
    const unsigned int* bR = base + agh * RS;    // block step within ci
    const unsigned int* bW = base + agh * 170;   // ky4 -> ky0, ci+1 wrap
    f32x4 acc = {0.f, 0.f, 0.f, 0.f};
#pragma unroll
    for (int c = 0; c < 15; ++c) {
      const int b0 = 2 * c;
      const int ci0 = b0 / 5, ky0 = b0 % 5;      // compile-time
      const unsigned int* pc =
          ((ky0 == 4) ? bW : bR) + (ci0 * PLANE + ky0 * RS);
      unsigned int a0 = pc[0], a1 = pc[1], a2 = pc[2], a3 = pc[3];
      union { u32x4 u; short8 s; } ua;
      ua.u = (u32x4){a0, a1, a2, a3};
      acc = __builtin_amdgcn_mfma_f32_16x16x32_bf16(ua.s, bf[c], acc, 0, 0, 0);
    }
    // lane's 4 C-rows = one 2x2 pool window (pool-block order)
    int po = t * 4 + ag;
    int imo = po / 25;
    int pbl = po - imo * 25;
    float v0 = acc[0] + bb, v1 = acc[1] + bb;
    float v2 = acc[2] + bb, v3 = acc[3] + bb;
    s0 += (v0 + v1) + (v2 + v3);
    q0 = fmaf(v0, v0, q0); q0 = fmaf(v1, v1, q0);
    q0 = fmaf(v2, v2, q0); q0 = fmaf(v3, v3, q0);
    float mx = fmaxf(fmaxf(v0, v1), fmaxf(v2, v3));
    m2[(size_t)(img0 + imo) * 400 + ch * 25 + pbl] = mx;
  }
  s0 += __shfl_xor(s0, 16, 64); q0 += __shfl_xor(q0, 16, 64);
  s0 += __shfl_xor(s0, 32, 64); q0 += __shfl_xor(q0, 32, 64);
  if (ag == 0) {
    atomicAdd(&red[ch], s0);
    atomicAdd(&redq[ch], q0);
  }
  __syncthreads();
  if (tid < 16) {
    int slot = blockIdx.x & 63;
    atomicAdd(&sums[SUM2 + tid * 64 + slot], (double)red[tid]);
    atomicAdd(&sums[SQ2 + tid * 64 + slot], (double)redq[tid]);
  }
}

// ---------------- layer 3: MFMA bf16-split GEMM — BN2 finalize in-kernel,
// whole A-tile staged once, barrier-free 25-chunk MFMA loop.
__global__ __launch_bounds__(256) void conv3_mfma(
    const float* __restrict__ m2, const unsigned short* __restrict__ wfr,
    const float* __restrict__ b3, const float* __restrict__ bn2_g,
    const float* __restrict__ bn2_b, double* __restrict__ sums,
    float* __restrict__ y3) {
  __shared__ unsigned int Alds[16 * 404];  // 25.9 KB
  __shared__ float sa2[16], sc2[16];
  __shared__ float red[128], redq[128];
  int tid = threadIdx.x;
  int img0 = blockIdx.x * 16;
  if (tid < 16) {  // in-kernel BN2 finalize (affine, eps 1e-4)
    const double* ps = sums + SUM2 + tid * 64;
    const double* pq = sums + SQ2 + tid * 64;
    double s = 0.0, q = 0.0;
#pragma unroll 8
    for (int i = 0; i < 64; ++i) { s += ps[i]; q += pq[i]; }
    double mean = s * (1.0 / (8192.0 * 100.0));
    double var = q * (1.0 / (8192.0 * 100.0)) - mean * mean;
    float inv = (float)(1.0 / sqrt(var + 1e-4));
    float g = fmaxf(bn2_g[tid], 0.01f);
    float av = g * inv;
    sa2[tid] = av;
    sc2[tid] = bn2_b[tid] - (float)mean * av;
  }
  if (tid < 128) { red[tid] = 0.f; redq[tid] = 0.f; }
  __syncthreads();
  // stage: 16 imgs x 400 k, BN2+relu, hi/lo pack -> u32
  for (int i4 = tid; i4 < 1600; i4 += 256) {
    int img = i4 / 100, k4 = i4 - img * 100;
    int k = 4 * k4;
    float4 v = *(const float4*)(m2 + (size_t)(img0 + img) * 400 + k);
    float vv[4] = {v.x, v.y, v.z, v.w};
    unsigned int pk[4];
#pragma unroll
    for (int e = 0; e < 4; ++e) {
      int ch = ((k + e) * 41) >> 10;  // /25
      float val = fmaxf(fmaf(sa2[ch], vv[e], sc2[ch]), 0.f);
      unsigned int hb = f2bf(val);
      float vh = __uint_as_float(hb << 16);
      unsigned int lb = f2bf(val - vh);
      pk[e] = hb | (lb << 16);
    }
    unsigned int* dst = &Alds[img * 404 + k];
    dst[0] = pk[0]; dst[1] = pk[1]; dst[2] = pk[2]; dst[3] = pk[3];
  }
  __syncthreads();

  int lane = tid & 63;
  int wv = tid >> 6;
  int nt0 = wv * 2, nt1 = wv * 2 + 1;
  const short8* bvec = (const short8*)wfr;
  int arow = lane & 15;
  int ag = lane >> 4;
  f32x4 acc0 = {0.f, 0.f, 0.f, 0.f}, acc1 = {0.f, 0.f, 0.f, 0.f};
  const unsigned short* abase =
      (const unsigned short*)&Alds[arow * 404 + ag * 4];
#pragma unroll 5
  for (int c = 0; c < 25; ++c) {
    short8 af = *(const short8*)(abase + c * 32);  // 16B aligned
    short8 b0 = bvec[(nt0 * 25 + c) * 64 + lane];
    short8 b1 = bvec[(nt1 * 25 + c) * 64 + lane];
    acc0 = __builtin_amdgcn_mfma_f32_16x16x32_bf16(af, b0, acc0, 0, 0, 0);
    acc1 = __builtin_amdgcn_mfma_f32_16x16x32_bf16(af, b1, acc1, 0, 0, 0);
  }
  int chA = nt0 * 16 + (lane & 15);
  int chB = nt1 * 16 + (lane & 15);
  int rbase = img0 + ((lane >> 4) << 2);
  {
    float bias = b3[chA];
    float s = 0.f, q = 0.f;
#pragma unroll
    for (int r = 0; r < 4; ++r) {
      float v = acc0[r] + bias;
      y3[(size_t)(rbase + r) * 120 + chA] = v;
      s += v; q = fmaf(v, v, q);
    }
    atomicAdd(&red[chA], s);
    atomicAdd(&redq[chA], q);
  }
  if (chB < 120) {
    float bias = b3[chB];
    float s = 0.f, q = 0.f;
#pragma unroll
    for (int r = 0; r < 4; ++r) {
      float v = acc1[r] + bias;
      y3[(size_t)(rbase + r) * 120 + chB] = v;
      s += v; q = fmaf(v, v, q);
    }
    atomicAdd(&red[chB], s);
    atomicAdd(&redq[chB], q);
  }
  __syncthreads();
  if (tid < 120) {
    int slot = blockIdx.x & 63;
    atomicAdd(&sums[SUM3 + tid * 64 + slot], (double)red[tid]);
    atomicAdd(&sums[SQ3 + tid * 64 + slot], (double)redq[tid]);
  }
}

// ---------------- fc: BN3 finalize in-kernel -> BN3+relu -> MFMA fc1 ->
// relu -> fc2. block 192 = 3 waves x 2 N-tiles. 16 imgs/block.
__global__ __launch_bounds__(192) void fc_mfma(
    const float* __restrict__ y3, const double* __restrict__ sums,
    const float* __restrict__ bn3_g, const float* __restrict__ bn3_b,
    const unsigned short* __restrict__ wfr2, const float* __restrict__ b1,
    const float* __restrict__ w2, const float* __restrict__ b2,
    float* __restrict__ out) {
  __shared__ unsigned int Alds[16 * 132];  // [img][k 0..127 pad] u32 hi|lo
  __shared__ float sh4[16 * 88];
  __shared__ float sw2[10 * 85];
  __shared__ float sa3[120], sc3[120];
  __shared__ float sb1[84], sb2[10];
  int tid = threadIdx.x;
  int img0 = blockIdx.x * 16;
  if (tid < 120) {  // in-kernel BN3 finalize (affine, eps 1e-5)
    const double* ps = sums + SUM3 + tid * 64;
    const double* pq = sums + SQ3 + tid * 64;
    double s = 0.0, q = 0.0;
#pragma unroll 8
    for (int i = 0; i < 64; ++i) { s += ps[i]; q += pq[i]; }
    double mean = s * (1.0 / 8192.0);
    double var = q * (1.0 / 8192.0) - mean * mean;
    float inv = (float)(1.0 / sqrt(var + 1e-5));
    float g = fmaxf(bn3_g[tid], 0.01f);
    float av = g * inv;
    sa3[tid] = av;
    sc3[tid] = bn3_b[tid] - (float)mean * av;
  }
  if (tid < 84) sb1[tid] = b1[tid];
  if (tid >= 84 && tid < 94) sb2[tid - 84] = b2[tid - 84];
  for (int i = tid; i < 850; i += 192) {
    int o = i / 85, k = i - o * 85;
    sw2[i] = (k < 84) ? w2[o * 84 + k] : 0.f;
  }
  __syncthreads();
  // stage: 16 imgs x 128 k (120 valid, pad zero), BN3+relu, hi/lo pack
  for (int i4 = tid; i4 < 512; i4 += 192) {
    int img = i4 >> 5, k4 = i4 & 31;
    int k = 4 * k4;
    unsigned int pk[4] = {0u, 0u, 0u, 0u};
    if (k4 < 30) {
      float4 v = *(const float4*)(y3 + (size_t)(img0 + img) * 120 + k);
      float vv[4] = {v.x, v.y, v.z, v.w};
#pragma unroll
      for (int e = 0; e < 4; ++e) {
        float val = fmaxf(fmaf(sa3[k + e], vv[e], sc3[k + e]), 0.f);
        unsigned int hb = f2bf(val);
        float vh = __uint_as_float(hb << 16);
        unsigned int lb = f2bf(val - vh);
        pk[e] = hb | (lb << 16);
      }
    }
    unsigned int* dst = &Alds[img * 132 + k];
    dst[0] = pk[0]; dst[1] = pk[1]; dst[2] = pk[2]; dst[3] = pk[3];
  }
  __syncthreads();

  int lane = tid & 63;
  int wv = tid >> 6;  // 0..2
  int nt0 = wv * 2, nt1 = wv * 2 + 1;
  const short8* bvec = (const short8*)wfr2;
  int arow = lane & 15;
  int ag = lane >> 4;
  f32x4 acc0 = {0.f, 0.f, 0.f, 0.f}, acc1 = {0.f, 0.f, 0.f, 0.f};
  const unsigned short* abase =
      (const unsigned short*)&Alds[arow * 132 + ag * 4];
#pragma unroll
  for (int c = 0; c < 8; ++c) {
    short8 af = *(const short8*)(abase + c * 32);
    short8 b0 = bvec[(nt0 * 8 + c) * 64 + lane];
    short8 b1 = bvec[(nt1 * 8 + c) * 64 + lane];
    acc0 = __builtin_amdgcn_mfma_f32_16x16x32_bf16(af, b0, acc0, 0, 0, 0);
    acc1 = __builtin_amdgcn_mfma_f32_16x16x32_bf16(af, b1, acc1, 0, 0, 0);
  }
  // h4 = relu(fc1 + b1) into LDS
  {
    int jA = nt0 * 16 + (lane & 15);  // <= 79, always valid
    int jB = nt1 * 16 + (lane & 15);  // may exceed 83
    int r0 = (lane >> 4) << 2;
#pragma unroll
    for (int r = 0; r < 4; ++r)
      sh4[(r0 + r) * 88 + jA] = fmaxf(acc0[r] + sb1[jA], 0.f);
    if (jB < 84) {
#pragma unroll
      for (int r = 0; r < 4; ++r)
        sh4[(r0 + r) * 88 + jB] = fmaxf(acc1[r] + sb1[jB], 0.f);
    }
  }
  __syncthreads();
  // fc2: 160 threads, one (img, out) each
  if (tid < 160) {
    int img = tid / 10, o = tid - (tid / 10) * 10;
    float acc = sb2[o];
    const float* hp = &sh4[img * 88];
    const float* wp = &sw2[o * 85];
#pragma unroll 4
    for (int k = 0; k < 84; ++k) acc = fmaf(hp[k], wp[k], acc);
    out[(size_t)(img0 + img) * 10 + o] = acc;
  }
}

extern "C" void kernel_launch(void* const* d_in, const int* in_sizes, int n_in,
                              void* d_out, int out_size, void* d_ws,
                              size_t ws_size, hipStream_t stream) {
  const float* x = (const float*)d_in[0];
  const float* conv1_w = (const float*)d_in[1];
  const float* conv1_b = (const float*)d_in[2];
  const float* conv2_w = (const float*)d_in[3];
  const float* conv2_b = (const float*)d_in[4];
  const float* bn2_g = (const float*)d_in[5];
  const float* bn2_b = (const float*)d_in[6];
  const float* conv3_w = (const float*)d_in[7];
  const float* conv3_b = (const float*)d_in[8];
  const float* bn3_g = (const float*)d_in[9];
  const float* bn3_b = (const float*)d_in[10];
  const float* fc1_w = (const float*)d_in[11];
  const float* fc1_b = (const float*)d_in[12];
  const float* fc2_w = (const float*)d_in[13];
  const float* fc2_b = (const float*)d_in[14];
  float* out = (float*)d_out;

  double* sums = (double*)d_ws;
  float* fbase = (float*)((char*)d_ws + DBL_BYTES);
  unsigned short* wfr = (unsigned short*)(fbase + WFR_OFF);
  unsigned short* wfr2 = (unsigned short*)(fbase + WFR2_OFF);
  float* m1 = fbase + H1_OFF;
  float* m2 = fbase + H2_OFF;
  float* y3 = fbase + Y3_OFF;
  unsigned short* wfr3 = (unsigned short*)y3;  // aliased; see layout note

  hipMemsetAsync(d_ws, 0, DBL_BYTES, stream);

  conv1_prep<<<1424, 256, 0, stream>>>(x, conv1_w, conv1_b, m1, sums, conv2_w,
                                       conv3_w, fc1_w, wfr3, wfr, wfr2);
  conv2_mfma<<<2048, 256, 0, stream>>>(m1, wfr3, conv2_b, sums, m2);
  conv3_mfma<<<512, 256, 0, stream>>>(m2, wfr, conv3_b, bn2_g, bn2_b, sums,
                                      y3);
  fc_mfma<<<512, 192, 0, stream>>>(y3, sums, bn3_g, bn3_b, wfr2, fc1_b, fc2_w,
                                   fc2_b, out);
}

// Round 12
// 196.663 us; speedup vs baseline: 1.0808x; 1.0151x over previous
//
#include <hip/hip_runtime.h>

#define DEVFN __device__ __forceinline__

DEVFN float sgnf(float x) { return (x > 0.f) ? 1.f : ((x < 0.f) ? -1.f : 0.f); }

// round-to-nearest-even fp32 -> bf16 bits
DEVFN unsigned short f2bf(float x) {
  unsigned int u = __float_as_uint(x);
  unsigned int r = (u + 0x7fffu + ((u >> 16) & 1u)) >> 16;
  return (unsigned short)r;
}

typedef __attribute__((ext_vector_type(8))) short short8;
typedef __attribute__((ext_vector_type(4))) float f32x4;
typedef __attribute__((ext_vector_type(2))) float f32x2;
typedef __attribute__((ext_vector_type(4))) unsigned int u32x4;

// ---- workspace layout ----
// double region (BN stat accumulators, 64 contention slots per channel)
#define SUM1 0        // 6*64 doubles
#define SQ1  384
#define SUM2 768      // 16*64
#define SQ2  1792
#define SUM3 2816     // 120*64
#define SQ3  10496
#define DBL_BYTES 145408  // 18176 doubles

// float region offsets (in floats, from fbase = ws + DBL_BYTES)
#define WFR_OFF  3584    // conv3 weights, bf16 frag image: 102400 ushort
#define WFR2_OFF 54784   // fc1 weights, bf16 frag image: 24576 ushort
#define H1_OFF   69632                  // 8192*1176 (pooled pre-BN layer1)
#define H2_OFF   (H1_OFF + 8192*1176)   // 8192*400  (pooled pre-BN layer2)
#define Y3_OFF   (H2_OFF + 8192*400)    // 8192*120  (pre-BN layer3)
// m1 is PAIR-INTERLEAVED: m1p[pair][e 0..1175][2] (q = img&1). conv1 writes
// each pool element for both pair images as one contiguous float2 (halves
// store instruction count, merges write lines); conv2's stage reads one
// coalesced float2 per element. Values identical to the flat layout.
// conv2 weight frag image (15 chunks x 64 lanes x 8 ushort = 7680) is
// ALIASED into the head of y3: written by prep, read by conv2_mfma,
// overwritten later by conv3_mfma. Stream-order safe, zero ws growth.

// conv2 staged-image geometry (u32 = hi|lo bf16 packed pixel).
// SINGLE copy, ODD row stride 17 (odd stride self-scrambles banks — the
// round-6 even-stride dual-copy variant hit 14.6M bank conflicts).
#define RS 17        // row stride: px(<=9) + kx(<=7) -> 17 cols; 14..16 zero
#define PLANE 238    // 14 * RS
#define IMGP 1428    // 6 * PLANE

// conv1 grid split: 1024 conv blocks (8 imgs) + 400 prep (R7-proven).
#define C1_NB 1024

// ---------------- layer 1 fused + weight-prep tail blocks ------------------
// blocks [0,1024): conv1 (conv + stats + pre-BN maxpool), image-PAIR packed
// via v_pk_fma_f32 (single rb buffer — R11's dbuf was neutral-negative).
// blocks [1024,1424): binarize/frag-image prep.
// LAUNCH BOUNDS NOTE: 2nd arg = MIN BLOCKS/CU on this toolchain (R8
// regression: (512,6) forced 40 VGPR -> 665 MB spill). (256,4) -> cap 128.
__global__ __launch_bounds__(256, 4) void conv1_prep(
    const float* __restrict__ x, const float* __restrict__ w1,
    const float* __restrict__ b1, float* __restrict__ m1,
    double* __restrict__ sums, const float* __restrict__ w2,
    const float* __restrict__ w3, const float* __restrict__ f1,
    unsigned short* __restrict__ wfr3, unsigned short* __restrict__ wfr,
    unsigned short* __restrict__ wfr2) {
  __shared__ f32x2 simg[4 * 1088];   // 4 img-pairs x 32 rows x 34 (pad)
  __shared__ float swtp[6 * 40];     // [ch][ky][8 pad] aligned weight rows
  __shared__ float red[6], redq[6];
  int tid = threadIdx.x;
  if (blockIdx.x >= C1_NB) {  // ---- prep path ----
    int i = (blockIdx.x - C1_NB) * 256 + tid;
    if (i < 7680) {  // conv2 frag image: kp = c*32 + 8g + j, k = kp>>1
      int j = i & 7;
      int t = i >> 3;
      int l = t & 63;
      int c = t >> 6;            // 0..14
      int ch = l & 15;
      int kp = c * 32 + ((l >> 4) << 3) + j;
      int k = kp >> 1;           // padded k, 0..239
      int b = k >> 3, kx = k & 7;
      int ci = b / 5, ky = b - 5 * ci;
      float v = (kx < 5) ? sgnf(w2[(ch * 6 + ci) * 25 + ky * 5 + kx]) : 0.f;
      wfr3[i] = f2bf(v);  // exact for -1/0/+1
    }
    if (i < 102400) {  // conv3 frag image: k' = c*32 + 8g + j, k = k'>>1
      int j = i & 7;
      int t = i >> 3;
      int l = t & 63;
      int cc = (t >> 6) % 25;
      int nt = (t >> 6) / 25;
      int ch = nt * 16 + (l & 15);
      int kp = cc * 32 + ((l >> 4) << 3) + j;
      float v = (ch < 120) ? sgnf(w3[ch * 400 + (kp >> 1)]) : 0.f;
      wfr[i] = f2bf(v);
    }
    if (i < 24576) {  // fc1 frag image: 6 nt x 8 c x 64 lane x 8
      int j = i & 7;
      int t = i >> 3;
      int l = t & 63;
      int cc = (t >> 6) & 7;
      int nt = t >> 9;
      int col = nt * 16 + (l & 15);
      int kp = cc * 32 + ((l >> 4) << 3) + j;
      int k = kp >> 1;
      float v = (col < 84 && k < 120) ? sgnf(f1[col * 120 + k]) : 0.f;
      wfr2[i] = f2bf(v);
    }
    return;
  }
  // ---- conv1 path ----
  int img0 = blockIdx.x * 8;
  int pair0 = blockIdx.x * 4;
  {
    const float2* xg = (const float2*)(x + (size_t)img0 * 1024);
    for (int i2 = tid; i2 < 4096; i2 += 256) {
      int img = i2 >> 9;   // 0..7
      int j = i2 & 511;
      float2 v = xg[img * 512 + j];
      int p = img >> 1, q = img & 1;
      int row = j >> 4, col = (j & 15) * 2;
      float* d0 = (float*)&simg[p * 1088 + row * 34 + col];
      d0[q] = v.x;
      d0[2 + q] = v.y;
    }
  }
  for (int i = tid; i < 240; i += 256) {  // [ch][ky][8]: kx<5 valid
    int ch = i / 40, r = i - ch * 40;
    int ky = r >> 3, kx = r & 7;
    swtp[i] = (kx < 5) ? w1[ch * 25 + ky * 5 + kx] : 0.f;
  }
  if (tid < 6) { red[tid] = 0.f; redq[tid] = 0.f; }
  __syncthreads();

  // items = 4 pairs x 14 pool-rows x 2 col-halves x 6 ch (ch fastest ->
  // rb reads broadcast across the 6-ch lane groups)
  for (int idx = tid; idx < 672; idx += 256) {
    int ch = idx % 6;
    int t = idx / 6;
    int h = t & 1;
    int t2 = t >> 1;
    int py = t2 % 14;
    int p = t2 / 14;
    float bb = b1[ch];
    f32x2 acc0[14], acc1[14];
#pragma unroll
    for (int o = 0; o < 14; ++o) {
      acc0[o] = (f32x2){bb, bb};
      acc1[o] = (f32x2){bb, bb};
    }
    const f32x2* ibase = &simg[p * 1088 + h * 14];
    const float* wch = &swtp[ch * 40];
#pragma unroll
    for (int d = 0; d < 6; ++d) {
      int row = 2 * py + d;
      f32x2 rb[18];
      const f32x4* rp = (const f32x4*)(ibase + row * 34);  // 16B aligned
#pragma unroll
      for (int tt = 0; tt < 9; ++tt) {
        f32x4 v = rp[tt];
        rb[2 * tt] = (f32x2){v.x, v.y};
        rb[2 * tt + 1] = (f32x2){v.z, v.w};
      }
      if (d < 5) {
        const float* wrow = wch + d * 8;
        f32x4 w4 = *(const f32x4*)wrow;   // 32B-aligned row
        float w5[5] = {w4.x, w4.y, w4.z, w4.w, wrow[4]};
#pragma unroll
        for (int kx = 0; kx < 5; ++kx) {
          f32x2 ws = {w5[kx], w5[kx]};
#pragma unroll
          for (int o = 0; o < 14; ++o)
            acc0[o] = __builtin_elementwise_fma(rb[o + kx], ws, acc0[o]);
        }
      }
      if (d >= 1) {
        const float* wrow = wch + (d - 1) * 8;
        f32x4 w4 = *(const f32x4*)wrow;
        float w5[5] = {w4.x, w4.y, w4.z, w4.w, wrow[4]};
#pragma unroll
        for (int kx = 0; kx < 5; ++kx) {
          f32x2 ws = {w5[kx], w5[kx]};
#pragma unroll
          for (int o = 0; o < 14; ++o)
            acc1[o] = __builtin_elementwise_fma(rb[o + kx], ws, acc1[o]);
        }
      }
    }
    // stats over this thread's 2 rows x 14 cols x 2 images
    f32x2 sv = {0.f, 0.f}, qv = {0.f, 0.f};
#pragma unroll
    for (int o = 0; o < 14; ++o) {
      f32x2 a0 = acc0[o], a1 = acc1[o];
      sv += a0; sv += a1;
      qv = __builtin_elementwise_fma(a0, a0, qv);
      qv = __builtin_elementwise_fma(a1, a1, qv);
    }
    atomicAdd(&red[ch], sv.x + sv.y);
    atomicAdd(&redq[ch], qv.x + qv.y);
    // pre-BN 2x2 maxpool -> pair-interleaved m1p: one contiguous 56B run
    // of float2 per item (was 14 scattered scalar stores)
    float* mp = m1 + (size_t)(pair0 + p) * 2352 +
                (ch * 196 + py * 14 + h * 7) * 2;
#pragma unroll
    for (int j = 0; j < 7; ++j) {
      f32x2 m = __builtin_elementwise_max(
          __builtin_elementwise_max(acc0[2 * j], acc0[2 * j + 1]),
          __builtin_elementwise_max(acc1[2 * j], acc1[2 * j + 1]));
      *(float2*)&mp[2 * j] = (float2){m.x, m.y};
    }
  }
  __syncthreads();
  if (tid < 6) {
    int slot = blockIdx.x & 63;
    atomicAdd(&sums[SUM1 + tid * 64 + slot], (double)red[tid]);
    atomicAdd(&sums[SQ1 + tid * 64 + slot], (double)redq[tid]);
  }
}

// ---------------- layer 2 as implicit-GEMM MFMA (round-4 proven LDS
// geometry: single copy, odd stride 17, 4x b32 A-frag reads). BN1 scales
// computed IN-KERNEL (producer completed by stream order; every block does
// the identical deterministic slot reduction). Reads pair-interleaved m1p.
__global__ __launch_bounds__(256, 4) void conv2_mfma(
    const float* __restrict__ m1, const unsigned short* __restrict__ wfr3,
    const float* __restrict__ b2, double* __restrict__ sums,
    float* __restrict__ m2) {
  __shared__ unsigned int Aim[4 * IMGP];  // 22.8 KB
  __shared__ float sa1[6], sc1[6];
  __shared__ float red[16], redq[16];
  int tid = threadIdx.x;
  int img0 = blockIdx.x * 4;
  if (tid < 6) {  // in-kernel BN1 finalize (no gamma/beta, eps 1e-4)
    const double* ps = sums + SUM1 + tid * 64;
    const double* pq = sums + SQ1 + tid * 64;
    double s = 0.0, q = 0.0;
#pragma unroll 8
    for (int i = 0; i < 64; ++i) { s += ps[i]; q += pq[i]; }
    double mean = s * (1.0 / (8192.0 * 784.0));
    double var = q * (1.0 / (8192.0 * 784.0)) - mean * mean;
    float inv = (float)(1.0 / sqrt(var + 1e-4));
    sa1[tid] = inv;
    sc1[tid] = -(float)mean * inv;
  }
  if (tid < 16) { red[tid] = 0.f; redq[tid] = 0.f; }
  // zero pad cols 14..16 (read only under zero weights; must be finite)
  for (int i = tid; i < 1008; i += 256) {
    int c3 = i - (i / 3) * 3;
    int t = i / 3;
    int row = t % 14;
    int t2 = t / 14;
    int ci = t2 % 6, img = t2 / 6;
    Aim[img * IMGP + ci * PLANE + row * RS + 14 + c3] = 0u;
  }
  __syncthreads();  // scales + pads ready
  {
    // m1p[pair][e][2]: one coalesced float2 = (imgA, imgB) at element e
    const float2* mg = (const float2*)(m1 + (size_t)img0 * 1176);
    for (int i2 = tid; i2 < 2352; i2 += 256) {
      int pr = i2 / 1176;          // pair within block (0..1)
      int e = i2 - pr * 1176;
      int pl = e / 196;
      int rr = e - pl * 196;
      int row = rr / 14, col = rr - row * 14;
      float a = sa1[pl], c = sc1[pl];
      float2 v = mg[i2];
      float v0 = fmaxf(fmaf(a, v.x, c), 0.f);
      float v1 = fmaxf(fmaf(a, v.y, c), 0.f);
      unsigned int h0 = f2bf(v0);
      unsigned int l0 = f2bf(v0 - __uint_as_float(h0 << 16));
      unsigned int h1 = f2bf(v1);
      unsigned int l1 = f2bf(v1 - __uint_as_float(h1 << 16));
      int off = pl * PLANE + row * RS + col;
      Aim[(2 * pr) * IMGP + off] = h0 | (l0 << 16);
      Aim[(2 * pr + 1) * IMGP + off] = h1 | (l1 << 16);
    }
  }
  __syncthreads();

  int lane = tid & 63;
  int wv = tid >> 6;
  const short8* bvec = (const short8*)wfr3;
  short8 bf[15];
#pragma unroll
  for (int c = 0; c < 15; ++c) bf[c] = bvec[c * 64 + lane];
  int ch = lane & 15;       // = A-row-in-tile AND output channel (C col)
  int ag = lane >> 4;       // k-group
  int agh = ag >> 1, agl = ag & 1;
  float bb = b2[ch];
  float s0 = 0.f, q0 = 0.f;

  for (int t = wv; t < 25; t += 4) {
    // A-read row: position p = t*16 + (lane&15), pool-block order
    int prd = t * 16 + ch;
    int imr = prd / 100;
    int pos = prd - imr * 100;
    int pb = pos >> 2, q = pos & 3;
    int pyr = pb / 5;
    int py = 2 * pyr + (q >> 1);
    int px = 2 * (pb - pyr * 5) + (q & 1);
    const unsigned int* base = &Aim[imr * IMGP + py * RS + px + agl * 4];
    const unsigned int* bR = base + agh * RS;    // block step within ci
    const unsigned int* bW = base + agh * 170;   // ky4 -> ky0, ci+1 wrap
    f32x4 acc = {0.f, 0.f, 0.f, 0.f};
#pragma unroll
    for (int c = 0; c < 15; ++c) {
      const int b0 = 2 * c;
      const int ci0 = b0 / 5, ky0 = b0 % 5;      // compile-time
      const unsigned int* pc =
          ((ky0 == 4) ? bW : bR) + (ci0 * PLANE + ky0 * RS);
      unsigned int a0 = pc[0], a1 = pc[1], a2 = pc[2], a3 = pc[3];
      union { u32x4 u; short8 s; } ua;
      ua.u = (u32x4){a0, a1, a2, a3};
      acc = __builtin_amdgcn_mfma_f32_16x16x32_bf16(ua.s, bf[c], acc, 0, 0, 0);
    }
    // lane's 4 C-rows = one 2x2 pool window (pool-block order)
    int po = t * 4 + ag;
    int imo = po / 25;
    int pbl = po - imo * 25;
    float v0 = acc[0] + bb, v1 = acc[1] + bb;
    float v2 = acc[2] + bb, v3 = acc[3] + bb;
    s0 += (v0 + v1) + (v2 + v3);
    q0 = fmaf(v0, v0, q0); q0 = fmaf(v1, v1, q0);
    q0 = fmaf(v2, v2, q0); q0 = fmaf(v3, v3, q0);
    float mx = fmaxf(fmaxf(v0, v1), fmaxf(v2, v3));
    m2[(size_t)(img0 + imo) * 400 + ch * 25 + pbl] = mx;
  }
  s0 += __shfl_xor(s0, 16, 64); q0 += __shfl_xor(q0, 16, 64);
  s0 += __shfl_xor(s0, 32, 64); q0 += __shfl_xor(q0, 32, 64);
  if (ag == 0) {
    atomicAdd(&red[ch], s0);
    atomicAdd(&redq[ch], q0);
  }
  __syncthreads();
  if (tid < 16) {
    int slot = blockIdx.x & 63;
    atomicAdd(&sums[SUM2 + tid * 64 + slot], (double)red[tid]);
    atomicAdd(&sums[SQ2 + tid * 64 + slot], (double)redq[tid]);
  }
}

// ---------------- layer 3: MFMA bf16-split GEMM — BN2 finalize in-kernel,
// whole A-tile staged once, barrier-free 25-chunk MFMA loop.
__global__ __launch_bounds__(256) void conv3_mfma(
    const float* __restrict__ m2, const unsigned short* __restrict__ wfr,
    const float* __restrict__ b3, const float* __restrict__ bn2_g,
    const float* __restrict__ bn2_b, double* __restrict__ sums,
    float* __restrict__ y3) {
  __shared__ unsigned int Alds[16 * 404];  // 25.9 KB
  __shared__ float sa2[16], sc2[16];
  __shared__ float red[128], redq[128];
  int tid = threadIdx.x;
  int img0 = blockIdx.x * 16;
  if (tid < 16) {  // in-kernel BN2 finalize (affine, eps 1e-4)
    const double* ps = sums + SUM2 + tid * 64;
    const double* pq = sums + SQ2 + tid * 64;
    double s = 0.0, q = 0.0;
#pragma unroll 8
    for (int i = 0; i < 64; ++i) { s += ps[i]; q += pq[i]; }
    double mean = s * (1.0 / (8192.0 * 100.0));
    double var = q * (1.0 / (8192.0 * 100.0)) - mean * mean;
    float inv = (float)(1.0 / sqrt(var + 1e-4));
    float g = fmaxf(bn2_g[tid], 0.01f);
    float av = g * inv;
    sa2[tid] = av;
    sc2[tid] = bn2_b[tid] - (float)mean * av;
  }
  if (tid < 128) { red[tid] = 0.f; redq[tid] = 0.f; }
  __syncthreads();
  // stage: 16 imgs x 400 k, BN2+relu, hi/lo pack -> u32
  for (int i4 = tid; i4 < 1600; i4 += 256) {
    int img = i4 / 100, k4 = i4 - img * 100;
    int k = 4 * k4;
    float4 v = *(const float4*)(m2 + (size_t)(img0 + img) * 400 + k);
    float vv[4] = {v.x, v.y, v.z, v.w};
    unsigned int pk[4];
#pragma unroll
    for (int e = 0; e < 4; ++e) {
      int ch = ((k + e) * 41) >> 10;  // /25
      float val = fmaxf(fmaf(sa2[ch], vv[e], sc2[ch]), 0.f);
      unsigned int hb = f2bf(val);
      float vh = __uint_as_float(hb << 16);
      unsigned int lb = f2bf(val - vh);
      pk[e] = hb | (lb << 16);
    }
    unsigned int* dst = &Alds[img * 404 + k];
    dst[0] = pk[0]; dst[1] = pk[1]; dst[2] = pk[2]; dst[3] = pk[3];
  }
  __syncthreads();

  int lane = tid & 63;
  int wv = tid >> 6;
  int nt0 = wv * 2, nt1 = wv * 2 + 1;
  const short8* bvec = (const short8*)wfr;
  int arow = lane & 15;
  int ag = lane >> 4;
  f32x4 acc0 = {0.f, 0.f, 0.f, 0.f}, acc1 = {0.f, 0.f, 0.f, 0.f};
  const unsigned short* abase =
      (const unsigned short*)&Alds[arow * 404 + ag * 4];
#pragma unroll 5
  for (int c = 0; c < 25; ++c) {
    short8 af = *(const short8*)(abase + c * 32);  // 16B aligned
    short8 b0 = bvec[(nt0 * 25 + c) * 64 + lane];
    short8 b1 = bvec[(nt1 * 25 + c) * 64 + lane];
    acc0 = __builtin_amdgcn_mfma_f32_16x16x32_bf16(af, b0, acc0, 0, 0, 0);
    acc1 = __builtin_amdgcn_mfma_f32_16x16x32_bf16(af, b1, acc1, 0, 0, 0);
  }
  int chA = nt0 * 16 + (lane & 15);
  int chB = nt1 * 16 + (lane & 15);
  int rbase = img0 + ((lane >> 4) << 2);
  {
    float bias = b3[chA];
    float s = 0.f, q = 0.f;
#pragma unroll
    for (int r = 0; r < 4; ++r) {
      float v = acc0[r] + bias;
      y3[(size_t)(rbase + r) * 120 + chA] = v;
      s += v; q = fmaf(v, v, q);
    }
    atomicAdd(&red[chA], s);
    atomicAdd(&redq[chA], q);
  }
  if (chB < 120) {
    float bias = b3[chB];
    float s = 0.f, q = 0.f;
#pragma unroll
    for (int r = 0; r < 4; ++r) {
      float v = acc1[r] + bias;
      y3[(size_t)(rbase + r) * 120 + chB] = v;
      s += v; q = fmaf(v, v, q);
    }
    atomicAdd(&red[chB], s);
    atomicAdd(&redq[chB], q);
  }
  __syncthreads();
  if (tid < 120) {
    int slot = blockIdx.x & 63;
    atomicAdd(&sums[SUM3 + tid * 64 + slot], (double)red[tid]);
    atomicAdd(&sums[SQ3 + tid * 64 + slot], (double)redq[tid]);
  }
}

// ---------------- fc: BN3 finalize in-kernel -> BN3+relu -> MFMA fc1 ->
// relu -> fc2. block 192 = 3 waves x 2 N-tiles. 16 imgs/block.
__global__ __launch_bounds__(192) void fc_mfma(
    const float* __restrict__ y3, const double* __restrict__ sums,
    const float* __restrict__ bn3_g, const float* __restrict__ bn3_b,
    const unsigned short* __restrict__ wfr2, const float* __restrict__ b1,
    const float* __restrict__ w2, const float* __restrict__ b2,
    float* __restrict__ out) {
  __shared__ unsigned int Alds[16 * 132];  // [img][k 0..127 pad] u32 hi|lo
  __shared__ float sh4[16 * 88];
  __shared__ float sw2[10 * 85];
  __shared__ float sa3[120], sc3[120];
  __shared__ float sb1[84], sb2[10];
  int tid = threadIdx.x;
  int img0 = blockIdx.x * 16;
  if (tid < 120) {  // in-kernel BN3 finalize (affine, eps 1e-5)
    const double* ps = sums + SUM3 + tid * 64;
    const double* pq = sums + SQ3 + tid * 64;
    double s = 0.0, q = 0.0;
#pragma unroll 8
    for (int i = 0; i < 64; ++i) { s += ps[i]; q += pq[i]; }
    double mean = s * (1.0 / 8192.0);
    double var = q * (1.0 / 8192.0) - mean * mean;
    float inv = (float)(1.0 / sqrt(var + 1e-5));
    float g = fmaxf(bn3_g[tid], 0.01f);
    float av = g * inv;
    sa3[tid] = av;
    sc3[tid] = bn3_b[tid] - (float)mean * av;
  }
  if (tid < 84) sb1[tid] = b1[tid];
  if (tid >= 84 && tid < 94) sb2[tid - 84] = b2[tid - 84];
  for (int i = tid; i < 850; i += 192) {
    int o = i / 85, k = i - o * 85;
    sw2[i] = (k < 84) ? w2[o * 84 + k] : 0.f;
  }
  __syncthreads();
  // stage: 16 imgs x 128 k (120 valid, pad zero), BN3+relu, hi/lo pack
  for (int i4 = tid; i4 < 512; i4 += 192) {
    int img = i4 >> 5, k4 = i4 & 31;
    int k = 4 * k4;
    unsigned int pk[4] = {0u, 0u, 0u, 0u};
    if (k4 < 30) {
      float4 v = *(const float4*)(y3 + (size_t)(img0 + img) * 120 + k);
      float vv[4] = {v.x, v.y, v.z, v.w};
#pragma unroll
      for (int e = 0; e < 4; ++e) {
        float val = fmaxf(fmaf(sa3[k + e], vv[e], sc3[k + e]), 0.f);
        unsigned int hb = f2bf(val);
        float vh = __uint_as_float(hb << 16);
        unsigned int lb = f2bf(val - vh);
        pk[e] = hb | (lb << 16);
      }
    }
    unsigned int* dst = &Alds[img * 132 + k];
    dst[0] = pk[0]; dst[1] = pk[1]; dst[2] = pk[2]; dst[3] = pk[3];
  }
  __syncthreads();

  int lane = tid & 63;
  int wv = tid >> 6;  // 0..2
  int nt0 = wv * 2, nt1 = wv * 2 + 1;
  const short8* bvec = (const short8*)wfr2;
  int arow = lane & 15;
  int ag = lane >> 4;
  f32x4 acc0 = {0.f, 0.f, 0.f, 0.f}, acc1 = {0.f, 0.f, 0.f, 0.f};
  const unsigned short* abase =
      (const unsigned short*)&Alds[arow * 132 + ag * 4];
#pragma unroll
  for (int c = 0; c < 8; ++c) {
    short8 af = *(const short8*)(abase + c * 32);
    short8 b0 = bvec[(nt0 * 8 + c) * 64 + lane];
    short8 b1 = bvec[(nt1 * 8 + c) * 64 + lane];
    acc0 = __builtin_amdgcn_mfma_f32_16x16x32_bf16(af, b0, acc0, 0, 0, 0);
    acc1 = __builtin_amdgcn_mfma_f32_16x16x32_bf16(af, b1, acc1, 0, 0, 0);
  }
  // h4 = relu(fc1 + b1) into LDS
  {
    int jA = nt0 * 16 + (lane & 15);  // <= 79, always valid
    int jB = nt1 * 16 + (lane & 15);  // may exceed 83
    int r0 = (lane >> 4) << 2;
#pragma unroll
    for (int r = 0; r < 4; ++r)
      sh4[(r0 + r) * 88 + jA] = fmaxf(acc0[r] + sb1[jA], 0.f);
    if (jB < 84) {
#pragma unroll
      for (int r = 0; r < 4; ++r)
        sh4[(r0 + r) * 88 + jB] = fmaxf(acc1[r] + sb1[jB], 0.f);
    }
  }
  __syncthreads();
  // fc2: 160 threads, one (img, out) each
  if (tid < 160) {
    int img = tid / 10, o = tid - (tid / 10) * 10;
    float acc = sb2[o];
    const float* hp = &sh4[img * 88];
    const float* wp = &sw2[o * 85];
#pragma unroll 4
    for (int k = 0; k < 84; ++k) acc = fmaf(hp[k], wp[k], acc);
    out[(size_t)(img0 + img) * 10 + o] = acc;
  }
}

extern "C" void kernel_launch(void* const* d_in, const int* in_sizes, int n_in,
                              void* d_out, int out_size, void* d_ws,
                              size_t ws_size, hipStream_t stream) {
  const float* x = (const float*)d_in[0];
  const float* conv1_w = (const float*)d_in[1];
  const float* conv1_b = (const float*)d_in[2];
  const float* conv2_w = (const float*)d_in[3];
  const float* conv2_b = (const float*)d_in[4];
  const float* bn2_g = (const float*)d_in[5];
  const float* bn2_b = (const float*)d_in[6];
  const float* conv3_w = (const float*)d_in[7];
  const float* conv3_b = (const float*)d_in[8];
  const float* bn3_g = (const float*)d_in[9];
  const float* bn3_b = (const float*)d_in[10];
  const float* fc1_w = (const float*)d_in[11];
  const float* fc1_b = (const float*)d_in[12];
  const float* fc2_w = (const float*)d_in[13];
  const float* fc2_b = (const float*)d_in[14];
  float* out = (float*)d_out;

  double* sums = (double*)d_ws;
  float* fbase = (float*)((char*)d_ws + DBL_BYTES);
  unsigned short* wfr = (unsigned short*)(fbase + WFR_OFF);
  unsigned short* wfr2 = (unsigned short*)(fbase + WFR2_OFF);
  float* m1 = fbase + H1_OFF;
  float* m2 = fbase + H2_OFF;
  float* y3 = fbase + Y3_OFF;
  unsigned short* wfr3 = (unsigned short*)y3;  // aliased; see layout note

  hipMemsetAsync(d_ws, 0, DBL_BYTES, stream);

  conv1_prep<<<1424, 256, 0, stream>>>(x, conv1_w, conv1_b, m1, sums, conv2_w,
                                       conv3_w, fc1_w, wfr3, wfr, wfr2);
  conv2_mfma<<<2048, 256, 0, stream>>>(m1, wfr3, conv2_b, sums, m2);
  conv3_mfma<<<512, 256, 0, stream>>>(m2, wfr, conv3_b, bn2_g, bn2_b, sums,
                                      y3);
  fc_mfma<<<512, 192, 0, stream>>>(y3, sums, bn3_g, bn3_b, wfr2, fc1_b, fc2_w,
                                   fc2_b, out);
}

// Round 13
// 189.754 us; speedup vs baseline: 1.1201x; 1.0364x over previous
//
#include <hip/hip_runtime.h>

#define DEVFN __device__ __forceinline__

DEVFN float sgnf(float x) { return (x > 0.f) ? 1.f : ((x < 0.f) ? -1.f : 0.f); }

// round-to-nearest-even fp32 -> bf16 bits
DEVFN unsigned short f2bf(float x) {
  unsigned int u = __float_as_uint(x);
  unsigned int r = (u + 0x7fffu + ((u >> 16) & 1u)) >> 16;
  return (unsigned short)r;
}

typedef __attribute__((ext_vector_type(8))) short short8;
typedef __attribute__((ext_vector_type(4))) float f32x4;
typedef __attribute__((ext_vector_type(2))) float f32x2;
typedef __attribute__((ext_vector_type(4))) unsigned int u32x4;

// ---- workspace layout ----
// double region (BN stat accumulators, 64 contention slots per channel)
#define SUM1 0        // 6*64 doubles
#define SQ1  384
#define SUM2 768      // 16*64
#define SQ2  1792
#define SUM3 2816     // 120*64
#define SQ3  10496
#define DBL_BYTES 145408  // 18176 doubles

// float region offsets (in floats, from fbase = ws + DBL_BYTES)
#define A1 0
#define C1 8
#define A2 16
#define C2 32
#define A3 48
#define C3 168
#define WFR_OFF  3584    // conv3 weights, bf16 frag image: 102400 ushort
#define WFR2_OFF 54784   // fc1 weights, bf16 frag image: 24576 ushort
#define H1_OFF   69632                  // 8192*1176 (pooled pre-BN layer1)
#define H2_OFF   (H1_OFF + 8192*1176)   // 8192*400  (pooled pre-BN layer2)
#define Y3_OFF   (H2_OFF + 8192*400)    // 8192*120  (pre-BN layer3)
// conv2 weight frag image (15 chunks x 64 lanes x 8 ushort = 7680) is
// ALIASED into the head of y3: written by prep, read by conv2_mfma,
// overwritten later by conv3_mfma. Stream-order safe, zero ws growth.

// conv2 staged-image geometry (u32 = hi|lo bf16 packed pixel)
#define RS 17        // row stride: px(<=9) + kx(<=7) -> 17 cols; 14..16 zero
#define PLANE 238    // 14 * RS
#define IMGP 1428    // 6 * PLANE

// ---------------- layer 1 fused + weight-prep tail blocks ------------------
// blocks [0,1024): conv1 (conv + stats + pre-BN maxpool), image-PAIR packed
// via v_pk_fma_f32 (f32x2 lanes = 2 images), same LDS footprint as scalar
// 8-img layout. blocks [1024,1424): binarize/frag-image prep.
__global__ __launch_bounds__(256, 4) void conv1_prep(
    const float* __restrict__ x, const float* __restrict__ w1,
    const float* __restrict__ b1, float* __restrict__ m1,
    double* __restrict__ sums, const float* __restrict__ w2,
    const float* __restrict__ w3, const float* __restrict__ f1,
    unsigned short* __restrict__ wfr3, unsigned short* __restrict__ wfr,
    unsigned short* __restrict__ wfr2) {
  __shared__ f32x2 simg[4 * 1088];   // 4 img-pairs x 32 rows x 34 (pad)
  __shared__ float swtp[6 * 40];     // [ch][ky][8 pad] aligned weight rows
  __shared__ float red[6], redq[6];
  int tid = threadIdx.x;
  if (blockIdx.x >= 1024) {  // ---- prep path ----
    int i = (blockIdx.x - 1024) * 256 + tid;
    if (i < 7680) {  // conv2 frag image: kp = c*32 + 8g + j, k = kp>>1
      int j = i & 7;
      int t = i >> 3;
      int l = t & 63;
      int c = t >> 6;            // 0..14
      int ch = l & 15;
      int kp = c * 32 + ((l >> 4) << 3) + j;
      int k = kp >> 1;           // padded k, 0..239
      int b = k >> 3, kx = k & 7;
      int ci = b / 5, ky = b - 5 * ci;
      float v = (kx < 5) ? sgnf(w2[(ch * 6 + ci) * 25 + ky * 5 + kx]) : 0.f;
      wfr3[i] = f2bf(v);  // exact for -1/0/+1
    }
    if (i < 102400) {  // conv3 frag image: k' = c*32 + 8g + j, k = k'>>1
      int j = i & 7;
      int t = i >> 3;
      int l = t & 63;
      int cc = (t >> 6) % 25;
      int nt = (t >> 6) / 25;
      int ch = nt * 16 + (l & 15);
      int kp = cc * 32 + ((l >> 4) << 3) + j;
      float v = (ch < 120) ? sgnf(w3[ch * 400 + (kp >> 1)]) : 0.f;
      wfr[i] = f2bf(v);
    }
    if (i < 24576) {  // fc1 frag image: 6 nt x 8 c x 64 lane x 8
      int j = i & 7;
      int t = i >> 3;
      int l = t & 63;
      int cc = (t >> 6) & 7;
      int nt = t >> 9;
      int col = nt * 16 + (l & 15);
      int kp = cc * 32 + ((l >> 4) << 3) + j;
      int k = kp >> 1;
      float v = (col < 84 && k < 120) ? sgnf(f1[col * 120 + k]) : 0.f;
      wfr2[i] = f2bf(v);
    }
    return;
  }
  // ---- conv1 path ----
  int img0 = blockIdx.x * 8;
  {
    const float2* xg = (const float2*)(x + (size_t)img0 * 1024);
    for (int i2 = tid; i2 < 4096; i2 += 256) {
      int img = i2 >> 9;   // 0..7
      int j = i2 & 511;
      float2 v = xg[img * 512 + j];
      int p = img >> 1, q = img & 1;
      int row = j >> 4, col = (j & 15) * 2;
      float* d0 = (float*)&simg[p * 1088 + row * 34 + col];
      d0[q] = v.x;
      d0[2 + q] = v.y;
    }
  }
  for (int i = tid; i < 240; i += 256) {  // [ch][ky][8]: kx<5 valid
    int ch = i / 40, r = i - ch * 40;
    int ky = r >> 3, kx = r & 7;
    swtp[i] = (kx < 5) ? w1[ch * 25 + ky * 5 + kx] : 0.f;
  }
  if (tid < 6) { red[tid] = 0.f; redq[tid] = 0.f; }
  __syncthreads();

  // 672 idx = 4 pairs x 14 pool-rows x 2 col-halves x 6 ch (ch fastest ->
  // rb reads broadcast across the 6-ch lane groups)
  for (int idx = tid; idx < 672; idx += 256) {
    int ch = idx % 6;
    int t = idx / 6;
    int h = t & 1;
    int t2 = t >> 1;
    int py = t2 % 14;
    int p = t2 / 14;
    float bb = b1[ch];
    f32x2 acc0[14], acc1[14];
#pragma unroll
    for (int o = 0; o < 14; ++o) {
      acc0[o] = (f32x2){bb, bb};
      acc1[o] = (f32x2){bb, bb};
    }
    const f32x2* ibase = &simg[p * 1088 + h * 14];
    const float* wch = &swtp[ch * 40];
#pragma unroll
    for (int d = 0; d < 6; ++d) {
      int row = 2 * py + d;
      f32x2 rb[18];
      const f32x4* rp = (const f32x4*)(ibase + row * 34);  // 16B aligned
#pragma unroll
      for (int tt = 0; tt < 9; ++tt) {
        f32x4 v = rp[tt];
        rb[2 * tt] = (f32x2){v.x, v.y};
        rb[2 * tt + 1] = (f32x2){v.z, v.w};
      }
      if (d < 5) {
        const float* wrow = wch + d * 8;
        f32x4 w4 = *(const f32x4*)wrow;   // 32B-aligned row
        float w5[5] = {w4.x, w4.y, w4.z, w4.w, wrow[4]};
#pragma unroll
        for (int kx = 0; kx < 5; ++kx) {
          f32x2 ws = {w5[kx], w5[kx]};
#pragma unroll
          for (int o = 0; o < 14; ++o)
            acc0[o] = __builtin_elementwise_fma(rb[o + kx], ws, acc0[o]);
        }
      }
      if (d >= 1) {
        const float* wrow = wch + (d - 1) * 8;
        f32x4 w4 = *(const f32x4*)wrow;
        float w5[5] = {w4.x, w4.y, w4.z, w4.w, wrow[4]};
#pragma unroll
        for (int kx = 0; kx < 5; ++kx) {
          f32x2 ws = {w5[kx], w5[kx]};
#pragma unroll
          for (int o = 0; o < 14; ++o)
            acc1[o] = __builtin_elementwise_fma(rb[o + kx], ws, acc1[o]);
        }
      }
    }
    // stats over this thread's 2 rows x 14 cols x 2 images
    f32x2 sv = {0.f, 0.f}, qv = {0.f, 0.f};
#pragma unroll
    for (int o = 0; o < 14; ++o) {
      f32x2 a0 = acc0[o], a1 = acc1[o];
      sv += a0; sv += a1;
      qv = __builtin_elementwise_fma(a0, a0, qv);
      qv = __builtin_elementwise_fma(a1, a1, qv);
    }
    atomicAdd(&red[ch], sv.x + sv.y);
    atomicAdd(&redq[ch], qv.x + qv.y);
    // pre-BN 2x2 maxpool, both images at once
    float* mpA = m1 + (size_t)(img0 + 2 * p) * 1176 + ch * 196 + py * 14 + h * 7;
    float* mpB = mpA + 1176;
#pragma unroll
    for (int j = 0; j < 7; ++j) {
      f32x2 m = __builtin_elementwise_max(
          __builtin_elementwise_max(acc0[2 * j], acc0[2 * j + 1]),
          __builtin_elementwise_max(acc1[2 * j], acc1[2 * j + 1]));
      mpA[j] = m.x;
      mpB[j] = m.y;
    }
  }
  __syncthreads();
  if (tid < 6) {
    int slot = blockIdx.x & 63;
    atomicAdd(&sums[SUM1 + tid * 64 + slot], (double)red[tid]);
    atomicAdd(&sums[SQ1 + tid * 64 + slot], (double)redq[tid]);
  }
}

// ---------------- BN finalize (parallel): wave per channel, coalesced ------
__global__ __launch_bounds__(256) void finalize_bn(
    const double* __restrict__ sum, const double* __restrict__ sq, int nch,
    double invN, double eps, const float* __restrict__ gamma,
    const float* __restrict__ beta, float* __restrict__ a,
    float* __restrict__ c) {
  int t = blockIdx.x * 256 + threadIdx.x;
  int ch = t >> 6, slot = t & 63;
  if (ch >= nch) return;
  double s = sum[ch * 64 + slot];
  double q = sq[ch * 64 + slot];
#pragma unroll
  for (int off = 32; off > 0; off >>= 1) {
    s += __shfl_down(s, off, 64);
    q += __shfl_down(q, off, 64);
  }
  if (slot == 0) {
    double mean = s * invN;
    double var = q * invN - mean * mean;
    float inv = (float)(1.0 / sqrt(var + eps));
    float g = gamma ? fmaxf(gamma[ch], 0.01f) : 1.f;
    float av = g * inv;
    float cv = (beta ? beta[ch] : 0.f) - (float)mean * av;
    a[ch] = av;
    c[ch] = cv;
  }
}

// ---------------- layer 2 as implicit-GEMM MFMA (binary weights, hi/lo
// bf16-split activations — same trick as conv3_mfma). M = positions in
// pool-block order (each lane's 4 C-rows = one 2x2 pool window), N = 16 ch,
// K = 6ci x 5ky x 8kx-pad = 480 bf16 = 15 chunks. A staged as [img][ci]
// [14][17] packed u32 image; per chunk the 4 u32 A-frag is contiguous.
// B-frags (15 x short8 = 60 VGPR) preloaded per wave. 4 imgs/block,
// 25 tiles/block, barrier-free main loop.
__global__ __launch_bounds__(256, 4) void conv2_mfma(
    const float* __restrict__ m1, const unsigned short* __restrict__ wfr3,
    const float* __restrict__ b2, const float* __restrict__ scales,
    float* __restrict__ m2, double* __restrict__ sums) {
  __shared__ unsigned int Aim[4 * IMGP];  // 22.8 KB
  __shared__ float sa1[6], sc1[6];
  __shared__ float red[16], redq[16];
  int tid = threadIdx.x;
  int img0 = blockIdx.x * 4;
  if (tid < 6) { sa1[tid] = scales[A1 + tid]; sc1[tid] = scales[C1 + tid]; }
  if (tid < 16) { red[tid] = 0.f; redq[tid] = 0.f; }
  // zero pad cols 14..16 (read only under zero weights; must be finite)
  for (int i = tid; i < 1008; i += 256) {
    int c3 = i - (i / 3) * 3;
    int t = i / 3;
    int row = t % 14;
    int t2 = t / 14;
    int ci = t2 % 6, img = t2 / 6;
    Aim[img * IMGP + ci * PLANE + row * RS + 14 + c3] = 0u;
  }
  __syncthreads();  // sa1/sc1 ready for staging
  {
    const float2* mg = (const float2*)(m1 + (size_t)img0 * 1176);
    for (int i2 = tid; i2 < 2352; i2 += 256) {
      int img = i2 / 588;
      int e = (i2 - img * 588) * 2;  // even element in [0,1176)
      int pl = e / 196;
      int rr = e - pl * 196;
      int row = rr / 14, col = rr - row * 14;  // col even, col+1 <= 13
      float a = sa1[pl], c = sc1[pl];
      float2 v = mg[i2];
      float v0 = fmaxf(fmaf(a, v.x, c), 0.f);
      float v1 = fmaxf(fmaf(a, v.y, c), 0.f);
      unsigned int h0 = f2bf(v0);
      unsigned int l0 = f2bf(v0 - __uint_as_float(h0 << 16));
      unsigned int h1 = f2bf(v1);
      unsigned int l1 = f2bf(v1 - __uint_as_float(h1 << 16));
      unsigned int* dst = &Aim[img * IMGP + pl * PLANE + row * RS + col];
      dst[0] = h0 | (l0 << 16);
      dst[1] = h1 | (l1 << 16);
    }
  }
  __syncthreads();

  int lane = tid & 63;
  int wv = tid >> 6;
  const short8* bvec = (const short8*)wfr3;
  short8 bf[15];
#pragma unroll
  for (int c = 0; c < 15; ++c) bf[c] = bvec[c * 64 + lane];
  int ch = lane & 15;       // = A-row-in-tile AND output channel (C col)
  int ag = lane >> 4;       // k-group
  int agh = ag >> 1, agl = ag & 1;
  float bb = b2[ch];
  float s0 = 0.f, q0 = 0.f;

  for (int t = wv; t < 25; t += 4) {
    // A-read row: position p = t*16 + (lane&15), pool-block order
    int prd = t * 16 + ch;
    int imr = prd / 100;
    int pos = prd - imr * 100;
    int pb = pos >> 2, q = pos & 3;
    int pyr = pb / 5;
    int py = 2 * pyr + (q >> 1);
    int px = 2 * (pb - pyr * 5) + (q & 1);
    const unsigned int* base = &Aim[imr * IMGP + py * RS + px + agl * 4];
    const unsigned int* bR = base + agh * RS;    // block step within ci
    const unsigned int* bW = base + agh * 170;   // ky4 -> ky0, ci+1 wrap
    f32x4 acc = {0.f, 0.f, 0.f, 0.f};
#pragma unroll
    for (int c = 0; c < 15; ++c) {
      const int b0 = 2 * c;
      const int ci0 = b0 / 5, ky0 = b0 % 5;      // compile-time
      const unsigned int* pc =
          ((ky0 == 4) ? bW : bR) + (ci0 * PLANE + ky0 * RS);
      unsigned int a0 = pc[0], a1 = pc[1], a2 = pc[2], a3 = pc[3];
      union { u32x4 u; short8 s; } ua;
      ua.u = (u32x4){a0, a1, a2, a3};
      acc = __builtin_amdgcn_mfma_f32_16x16x32_bf16(ua.s, bf[c], acc, 0, 0, 0);
    }
    // lane's 4 C-rows = one 2x2 pool window (pool-block order)
    int po = t * 4 + ag;
    int imo = po / 25;
    int pbl = po - imo * 25;
    float v0 = acc[0] + bb, v1 = acc[1] + bb;
    float v2 = acc[2] + bb, v3 = acc[3] + bb;
    s0 += (v0 + v1) + (v2 + v3);
    q0 = fmaf(v0, v0, q0); q0 = fmaf(v1, v1, q0);
    q0 = fmaf(v2, v2, q0); q0 = fmaf(v3, v3, q0);
    float mx = fmaxf(fmaxf(v0, v1), fmaxf(v2, v3));
    m2[(size_t)(img0 + imo) * 400 + ch * 25 + pbl] = mx;
  }
  s0 += __shfl_xor(s0, 16, 64); q0 += __shfl_xor(q0, 16, 64);
  s0 += __shfl_xor(s0, 32, 64); q0 += __shfl_xor(q0, 32, 64);
  if (ag == 0) {
    atomicAdd(&red[ch], s0);
    atomicAdd(&redq[ch], q0);
  }
  __syncthreads();
  if (tid < 16) {
    int slot = blockIdx.x & 63;
    atomicAdd(&sums[SUM2 + tid * 64 + slot], (double)red[tid]);
    atomicAdd(&sums[SQ2 + tid * 64 + slot], (double)redq[tid]);
  }
}

// ---------------- layer 3: MFMA bf16-split GEMM — whole A-tile staged once
// (u32 hi|lo packed, [img][k] stride 404), barrier-free 25-chunk MFMA loop.
__global__ __launch_bounds__(256) void conv3_mfma(
    const float* __restrict__ m2, const unsigned short* __restrict__ wfr,
    const float* __restrict__ b3, const float* __restrict__ scales,
    float* __restrict__ y3, double* __restrict__ sums) {
  __shared__ unsigned int Alds[16 * 404];  // 25.9 KB
  __shared__ float sa2[16], sc2[16];
  __shared__ float red[128], redq[128];
  int tid = threadIdx.x;
  int img0 = blockIdx.x * 16;
  if (tid < 16) { sa2[tid] = scales[A2 + tid]; sc2[tid] = scales[C2 + tid]; }
  if (tid < 128) { red[tid] = 0.f; redq[tid] = 0.f; }
  __syncthreads();
  // stage: 16 imgs x 400 k, BN2+relu, hi/lo pack -> u32
  for (int i4 = tid; i4 < 1600; i4 += 256) {
    int img = i4 / 100, k4 = i4 - img * 100;
    int k = 4 * k4;
    float4 v = *(const float4*)(m2 + (size_t)(img0 + img) * 400 + k);
    float vv[4] = {v.x, v.y, v.z, v.w};
    unsigned int pk[4];
#pragma unroll
    for (int e = 0; e < 4; ++e) {
      int ch = ((k + e) * 41) >> 10;  // /25
      float val = fmaxf(fmaf(sa2[ch], vv[e], sc2[ch]), 0.f);
      unsigned int hb = f2bf(val);
      float vh = __uint_as_float(hb << 16);
      unsigned int lb = f2bf(val - vh);
      pk[e] = hb | (lb << 16);
    }
    unsigned int* dst = &Alds[img * 404 + k];
    dst[0] = pk[0]; dst[1] = pk[1]; dst[2] = pk[2]; dst[3] = pk[3];
  }
  __syncthreads();

  int lane = tid & 63;
  int wv = tid >> 6;
  int nt0 = wv * 2, nt1 = wv * 2 + 1;
  const short8* bvec = (const short8*)wfr;
  int arow = lane & 15;
  int ag = lane >> 4;
  f32x4 acc0 = {0.f, 0.f, 0.f, 0.f}, acc1 = {0.f, 0.f, 0.f, 0.f};
  const unsigned short* abase =
      (const unsigned short*)&Alds[arow * 404 + ag * 4];
#pragma unroll 5
  for (int c = 0; c < 25; ++c) {
    short8 af = *(const short8*)(abase + c * 32);  // 16B aligned
    short8 b0 = bvec[(nt0 * 25 + c) * 64 + lane];
    short8 b1 = bvec[(nt1 * 25 + c) * 64 + lane];
    acc0 = __builtin_amdgcn_mfma_f32_16x16x32_bf16(af, b0, acc0, 0, 0, 0);
    acc1 = __builtin_amdgcn_mfma_f32_16x16x32_bf16(af, b1, acc1, 0, 0, 0);
  }
  int chA = nt0 * 16 + (lane & 15);
  int chB = nt1 * 16 + (lane & 15);
  int rbase = img0 + ((lane >> 4) << 2);
  {
    float bias = b3[chA];
    float s = 0.f, q = 0.f;
#pragma unroll
    for (int r = 0; r < 4; ++r) {
      float v = acc0[r] + bias;
      y3[(size_t)(rbase + r) * 120 + chA] = v;
      s += v; q = fmaf(v, v, q);
    }
    atomicAdd(&red[chA], s);
    atomicAdd(&redq[chA], q);
  }
  if (chB < 120) {
    float bias = b3[chB];
    float s = 0.f, q = 0.f;
#pragma unroll
    for (int r = 0; r < 4; ++r) {
      float v = acc1[r] + bias;
      y3[(size_t)(rbase + r) * 120 + chB] = v;
      s += v; q = fmaf(v, v, q);
    }
    atomicAdd(&red[chB], s);
    atomicAdd(&redq[chB], q);
  }
  __syncthreads();
  if (tid < 120) {
    int slot = blockIdx.x & 63;
    atomicAdd(&sums[SUM3 + tid * 64 + slot], (double)red[tid]);
    atomicAdd(&sums[SQ3 + tid * 64 + slot], (double)redq[tid]);
  }
}

// ---------------- fc: BN3+relu -> MFMA fc1(binary, bf16-split) -> relu -> fc2
// block 192 = 3 waves x 2 N-tiles (N=96 pad, 84 valid). 16 imgs/block.
__global__ __launch_bounds__(192) void fc_mfma(
    const float* __restrict__ y3, const float* __restrict__ scales,
    const unsigned short* __restrict__ wfr2, const float* __restrict__ b1,
    const float* __restrict__ w2, const float* __restrict__ b2,
    float* __restrict__ out) {
  __shared__ unsigned int Alds[16 * 132];  // [img][k 0..127 pad] u32 hi|lo
  __shared__ float sh4[16 * 88];
  __shared__ float sw2[10 * 85];
  __shared__ float sa3[120], sc3[120];
  __shared__ float sb1[84], sb2[10];
  int tid = threadIdx.x;
  int img0 = blockIdx.x * 16;
  if (tid < 120) { sa3[tid] = scales[A3 + tid]; sc3[tid] = scales[C3 + tid]; }
  if (tid < 84) sb1[tid] = b1[tid];
  if (tid >= 84 && tid < 94) sb2[tid - 84] = b2[tid - 84];
  for (int i = tid; i < 850; i += 192) {
    int o = i / 85, k = i - o * 85;
    sw2[i] = (k < 84) ? w2[o * 84 + k] : 0.f;
  }
  __syncthreads();
  // stage: 16 imgs x 128 k (120 valid, pad zero), BN3+relu, hi/lo pack
  for (int i4 = tid; i4 < 512; i4 += 192) {
    int img = i4 >> 5, k4 = i4 & 31;
    int k = 4 * k4;
    unsigned int pk[4] = {0u, 0u, 0u, 0u};
    if (k4 < 30) {
      float4 v = *(const float4*)(y3 + (size_t)(img0 + img) * 120 + k);
      float vv[4] = {v.x, v.y, v.z, v.w};
#pragma unroll
      for (int e = 0; e < 4; ++e) {
        float val = fmaxf(fmaf(sa3[k + e], vv[e], sc3[k + e]), 0.f);
        unsigned int hb = f2bf(val);
        float vh = __uint_as_float(hb << 16);
        unsigned int lb = f2bf(val - vh);
        pk[e] = hb | (lb << 16);
      }
    }
    unsigned int* dst = &Alds[img * 132 + k];
    dst[0] = pk[0]; dst[1] = pk[1]; dst[2] = pk[2]; dst[3] = pk[3];
  }
  __syncthreads();

  int lane = tid & 63;
  int wv = tid >> 6;  // 0..2
  int nt0 = wv * 2, nt1 = wv * 2 + 1;
  const short8* bvec = (const short8*)wfr2;
  int arow = lane & 15;
  int ag = lane >> 4;
  f32x4 acc0 = {0.f, 0.f, 0.f, 0.f}, acc1 = {0.f, 0.f, 0.f, 0.f};
  const unsigned short* abase =
      (const unsigned short*)&Alds[arow * 132 + ag * 4];
#pragma unroll
  for (int c = 0; c < 8; ++c) {
    short8 af = *(const short8*)(abase + c * 32);
    short8 b0 = bvec[(nt0 * 8 + c) * 64 + lane];
    short8 b1 = bvec[(nt1 * 8 + c) * 64 + lane];
    acc0 = __builtin_amdgcn_mfma_f32_16x16x32_bf16(af, b0, acc0, 0, 0, 0);
    acc1 = __builtin_amdgcn_mfma_f32_16x16x32_bf16(af, b1, acc1, 0, 0, 0);
  }
  // h4 = relu(fc1 + b1) into LDS
  {
    int jA = nt0 * 16 + (lane & 15);  // <= 79, always valid
    int jB = nt1 * 16 + (lane & 15);  // may exceed 83
    int r0 = (lane >> 4) << 2;
#pragma unroll
    for (int r = 0; r < 4; ++r)
      sh4[(r0 + r) * 88 + jA] = fmaxf(acc0[r] + sb1[jA], 0.f);
    if (jB < 84) {
#pragma unroll
      for (int r = 0; r < 4; ++r)
        sh4[(r0 + r) * 88 + jB] = fmaxf(acc1[r] + sb1[jB], 0.f);
    }
  }
  __syncthreads();
  // fc2: 160 threads, one (img, out) each
  if (tid < 160) {
    int img = tid / 10, o = tid - (tid / 10) * 10;
    float acc = sb2[o];
    const float* hp = &sh4[img * 88];
    const float* wp = &sw2[o * 85];
#pragma unroll 4
    for (int k = 0; k < 84; ++k) acc = fmaf(hp[k], wp[k], acc);
    out[(size_t)(img0 + img) * 10 + o] = acc;
  }
}

extern "C" void kernel_launch(void* const* d_in, const int* in_sizes, int n_in,
                              void* d_out, int out_size, void* d_ws,
                              size_t ws_size, hipStream_t stream) {
  const float* x = (const float*)d_in[0];
  const float* conv1_w = (const float*)d_in[1];
  const float* conv1_b = (const float*)d_in[2];
  const float* conv2_w = (const float*)d_in[3];
  const float* conv2_b = (const float*)d_in[4];
  const float* bn2_g = (const float*)d_in[5];
  const float* bn2_b = (const float*)d_in[6];
  const float* conv3_w = (const float*)d_in[7];
  const float* conv3_b = (const float*)d_in[8];
  const float* bn3_g = (const float*)d_in[9];
  const float* bn3_b = (const float*)d_in[10];
  const float* fc1_w = (const float*)d_in[11];
  const float* fc1_b = (const float*)d_in[12];
  const float* fc2_w = (const float*)d_in[13];
  const float* fc2_b = (const float*)d_in[14];
  float* out = (float*)d_out;

  double* sums = (double*)d_ws;
  float* fbase = (float*)((char*)d_ws + DBL_BYTES);
  float* scales = fbase;
  unsigned short* wfr = (unsigned short*)(fbase + WFR_OFF);
  unsigned short* wfr2 = (unsigned short*)(fbase + WFR2_OFF);
  float* m1 = fbase + H1_OFF;
  float* m2 = fbase + H2_OFF;
  float* y3 = fbase + Y3_OFF;
  unsigned short* wfr3 = (unsigned short*)y3;  // aliased; see layout note

  hipMemsetAsync(d_ws, 0, DBL_BYTES, stream);

  conv1_prep<<<1424, 256, 0, stream>>>(x, conv1_w, conv1_b, m1, sums, conv2_w,
                                       conv3_w, fc1_w, wfr3, wfr, wfr2);
  finalize_bn<<<2, 256, 0, stream>>>(sums + SUM1, sums + SQ1, 6,
                                     1.0 / (8192.0 * 784.0), 1e-4, nullptr,
                                     nullptr, scales + A1, scales + C1);

  conv2_mfma<<<2048, 256, 0, stream>>>(m1, wfr3, conv2_b, scales, m2, sums);
  finalize_bn<<<4, 256, 0, stream>>>(sums + SUM2, sums + SQ2, 16,
                                     1.0 / (8192.0 * 100.0), 1e-4, bn2_g, bn2_b,
                                     scales + A2, scales + C2);

  conv3_mfma<<<512, 256, 0, stream>>>(m2, wfr, conv3_b, scales, y3, sums);
  finalize_bn<<<30, 256, 0, stream>>>(sums + SUM3, sums + SQ3, 120,
                                      1.0 / 8192.0, 1e-5, bn3_g, bn3_b,
                                      scales + A3, scales + C3);

  fc_mfma<<<512, 192, 0, stream>>>(y3, scales, wfr2, fc1_b, fc2_w, fc2_b, out);
}